// Round 1
// baseline (903.106 us; speedup 1.0000x reference)
//
#include <hip/hip_runtime.h>
#include <cstdint>
#include <cstddef>

#define NEG_SLOPE 0.2f
#define EPS_BN 1e-5f

static __device__ __forceinline__ float lrelu(float x){ return x > 0.f ? x : NEG_SLOPE * x; }

static inline int ceil_div(int a, int b){ return (a + b - 1) / b; }

// ---------------- utility kernels ----------------

__global__ void fill_u32_kernel(unsigned* __restrict__ p, unsigned v, int n){
  int i = blockIdx.x * 256 + threadIdx.x;
  if(i < n) p[i] = v;
}

__global__ void copy_i32_kernel(const int* __restrict__ a, int* __restrict__ b, int n){
  int i = blockIdx.x * 256 + threadIdx.x;
  if(i < n) b[i] = a[i];
}

// ---------------- CSR build (dst-sorted adjacency) ----------------

__global__ void hist_kernel(const int* __restrict__ ei, int* __restrict__ deg, int E, int N){
  int e = blockIdx.x * 256 + threadIdx.x;
  if(e >= E + N) return;
  int d = (e < E) ? ei[E + e] : (e - E);   // self loop for e >= E
  atomicAdd(&deg[d], 1);
}

__global__ __launch_bounds__(1024) void scan_kernel(const int* __restrict__ deg, int* __restrict__ rowptr, int n){
  __shared__ int smem[1024];
  __shared__ int carry_s;
  int t = threadIdx.x;
  if(t == 0){ carry_s = 0; rowptr[0] = 0; }
  __syncthreads();
  for(int base = 0; base < n; base += 1024){
    int i = base + t;
    int v = (i < n) ? deg[i] : 0;
    smem[t] = v;
    __syncthreads();
    for(int off = 1; off < 1024; off <<= 1){
      int tv = (t >= off) ? smem[t - off] : 0;
      __syncthreads();
      smem[t] += tv;
      __syncthreads();
    }
    int inc = smem[t] + carry_s;           // inclusive prefix + carry
    if(i < n) rowptr[i + 1] = inc;
    __syncthreads();
    if(t == 1023) carry_s = inc;
    __syncthreads();
  }
}

__global__ void scatter_kernel(const int* __restrict__ ei, int* __restrict__ cur, int* __restrict__ col, int E, int N){
  int e = blockIdx.x * 256 + threadIdx.x;
  if(e >= E + N) return;
  int s, d;
  if(e < E){ s = ei[e]; d = ei[E + e]; } else { s = e - E; d = e - E; }
  int pos = atomicAdd(&cur[d], 1);
  col[pos] = s;
}

// ---------------- GEMM: C[MxN] = A[MxK] @ B[KxN], row-major ----------------

__global__ __launch_bounds__(256) void gemm_kernel(const float* __restrict__ A, const float* __restrict__ B,
                                                   float* __restrict__ C, int M, int N, int K){
  const int BM = 64, BN = 64, BK = 16, TM = 4, TN = 4;
  __shared__ float As[BK][BM + 1];
  __shared__ float Bs[BK][BN + 1];
  int tid = threadIdx.x;
  int tx = tid % 16, ty = tid / 16;
  int row0 = blockIdx.x * BM;
  int col0 = blockIdx.y * BN;
  float acc[TM][TN] = {};
  for(int k0 = 0; k0 < K; k0 += BK){
    #pragma unroll
    for(int i = 0; i < (BM * BK) / 256; i++){
      int idx = tid + i * 256;
      int r = idx / BK, kk = idx % BK;
      int gr = row0 + r, gk = k0 + kk;
      As[kk][r] = (gr < M && gk < K) ? A[(size_t)gr * K + gk] : 0.f;
    }
    #pragma unroll
    for(int i = 0; i < (BK * BN) / 256; i++){
      int idx = tid + i * 256;
      int kk = idx / BN, c = idx % BN;
      int gk = k0 + kk, gc = col0 + c;
      Bs[kk][c] = (gk < K && gc < N) ? B[(size_t)gk * N + gc] : 0.f;
    }
    __syncthreads();
    #pragma unroll
    for(int kk = 0; kk < BK; kk++){
      float a[TM], b[TN];
      #pragma unroll
      for(int i = 0; i < TM; i++) a[i] = As[kk][ty * TM + i];
      #pragma unroll
      for(int j = 0; j < TN; j++) b[j] = Bs[kk][tx * TN + j];
      #pragma unroll
      for(int i = 0; i < TM; i++)
        #pragma unroll
        for(int j = 0; j < TN; j++) acc[i][j] += a[i] * b[j];
    }
    __syncthreads();
  }
  #pragma unroll
  for(int i = 0; i < TM; i++){
    int gr = row0 + ty * TM + i;
    if(gr >= M) continue;
    #pragma unroll
    for(int j = 0; j < TN; j++){
      int gc = col0 + tx * TN + j;
      if(gc >= N) continue;
      C[(size_t)gr * N + gc] = acc[i][j];
    }
  }
}

// ---------------- alpha_src / alpha_dst dot products ----------------
// h layout [N, H*64] viewed as [(N*H), 64]; one wave per (node, head).

__global__ void alpha_kernel(const float* __restrict__ h, const float* __restrict__ a_src, const float* __restrict__ a_dst,
                             float* __restrict__ as_, float* __restrict__ ad_, int NH, int H){
  int wid = threadIdx.x >> 6, lane = threadIdx.x & 63;
  int gw = blockIdx.x * 4 + wid;
  if(gw >= NH) return;
  int hh = gw % H;
  float v = h[(size_t)gw * 64 + lane];
  float ps = v * a_src[hh * 64 + lane];
  float pd = v * a_dst[hh * 64 + lane];
  #pragma unroll
  for(int off = 32; off; off >>= 1){
    ps += __shfl_xor(ps, off);
    pd += __shfl_xor(pd, off);
  }
  if(lane == 0){ as_[gw] = ps; ad_[gw] = pd; }
}

// ---------------- GAT aggregation: one wave per destination node ----------------
// segment softmax (max, sum) + weighted feature accumulation, no atomics.

template<int H>
__global__ __launch_bounds__(256) void gat_aggregate_kernel(const float* __restrict__ hfeat, const float* __restrict__ as_,
                                                            const float* __restrict__ ad_, const int* __restrict__ rowptr,
                                                            const int* __restrict__ col, const float* __restrict__ bias,
                                                            float* __restrict__ out, int N){
  int wid = threadIdx.x >> 6, lane = threadIdx.x & 63;
  int n = blockIdx.x * 4 + wid;
  if(n >= N) return;
  int start = rowptr[n], end = rowptr[n + 1];
  float adn[H], m[H], den[H], acc[H];
  #pragma unroll
  for(int h = 0; h < H; h++){ adn[h] = ad_[n * H + h]; m[h] = -1e30f; den[h] = 0.f; acc[h] = 0.f; }
  // phase A: segment max (lanes split edges)
  for(int j = start + lane; j < end; j += 64){
    int s = col[j];
    #pragma unroll
    for(int h = 0; h < H; h++){
      float l = lrelu(as_[s * H + h] + adn[h]);
      m[h] = fmaxf(m[h], l);
    }
  }
  #pragma unroll
  for(int h = 0; h < H; h++)
    for(int off = 32; off; off >>= 1) m[h] = fmaxf(m[h], __shfl_xor(m[h], off));
  // phase B: denominator
  for(int j = start + lane; j < end; j += 64){
    int s = col[j];
    #pragma unroll
    for(int h = 0; h < H; h++){
      float l = lrelu(as_[s * H + h] + adn[h]);
      den[h] += __expf(l - m[h]);
    }
  }
  #pragma unroll
  for(int h = 0; h < H; h++){
    for(int off = 32; off; off >>= 1) den[h] += __shfl_xor(den[h], off);
    den[h] = 1.f / (den[h] + 1e-16f);
  }
  // phase C: weighted accumulate, whole wave walks edges, lane = channel
  for(int j = start; j < end; j++){
    int s = col[j];
    const float* hr = hfeat + (size_t)s * (H * 64);
    #pragma unroll
    for(int h = 0; h < H; h++){
      float l = lrelu(as_[s * H + h] + adn[h]);
      float a = __expf(l - m[h]) * den[h];
      acc[h] += a * hr[h * 64 + lane];
    }
  }
  #pragma unroll
  for(int h = 0; h < H; h++)
    out[(size_t)n * (H * 64) + h * 64 + lane] = acc[h] + bias[h * 64 + lane];
}

// ---------------- BatchNorm: column stats then normalize (+optional ELU) ----------------

__global__ __launch_bounds__(256) void colstats_kernel(const float* __restrict__ x, float* __restrict__ stats, int N, int C){
  int t = threadIdx.x;
  int rpb = 256 / C;            // rows per block-iteration (C in {64,128,256})
  int c = t % C;
  int rg = t / C;
  float sum = 0.f, sq = 0.f;
  for(int r = blockIdx.x * rpb + rg; r < N; r += gridDim.x * rpb){
    float v = x[(size_t)r * C + c];
    sum += v; sq += v * v;
  }
  __shared__ float ssum[256], ssq[256];
  ssum[t] = sum; ssq[t] = sq;
  __syncthreads();
  if(t < C){
    float S = 0.f, Q = 0.f;
    for(int g = 0; g < rpb; g++){ S += ssum[g * C + t]; Q += ssq[g * C + t]; }
    atomicAdd(&stats[t], S);
    atomicAdd(&stats[C + t], Q);
  }
}

__global__ void bn_act_kernel(const float* __restrict__ x, const float* __restrict__ stats,
                              const float* __restrict__ gamma, const float* __restrict__ beta,
                              float* __restrict__ y, int N, int C, int do_elu){
  size_t i = (size_t)blockIdx.x * 256 + threadIdx.x;
  if(i >= (size_t)N * C) return;
  int c = (int)(i & (size_t)(C - 1));     // C is a power of two
  float invN = 1.f / (float)N;
  float mu = stats[c] * invN;
  float var = stats[C + c] * invN - mu * mu;
  float v = (x[i] - mu) * rsqrtf(var + EPS_BN) * gamma[c] + beta[c];
  if(do_elu) v = v > 0.f ? v : expm1f(v);
  y[i] = v;
}

// ---------------- launch ----------------

extern "C" void kernel_launch(void* const* d_in, const int* in_sizes, int n_in,
                              void* d_out, int out_size, void* d_ws, size_t ws_size,
                              hipStream_t stream){
  const float* x   = (const float*)d_in[0];
  const int*   ei  = (const int*)  d_in[1];
  const float* W1  = (const float*)d_in[2];
  const float* a1s = (const float*)d_in[3];
  const float* a1d = (const float*)d_in[4];
  const float* b1  = (const float*)d_in[5];
  const float* W2  = (const float*)d_in[6];
  const float* a2s = (const float*)d_in[7];
  const float* a2d = (const float*)d_in[8];
  const float* b2  = (const float*)d_in[9];
  const float* Wp  = (const float*)d_in[10];
  const float* g1  = (const float*)d_in[12]; const float* be1 = (const float*)d_in[13];
  const float* g2  = (const float*)d_in[14]; const float* be2 = (const float*)d_in[15];
  const float* g3  = (const float*)d_in[16]; const float* be3 = (const float*)d_in[17];
  float* out = (float*)d_out;

  const int N  = in_sizes[0] / 128;
  const int E  = in_sizes[1] / 2;
  const int EP = E + N;

  // workspace carve (~103 MB total)
  char* w = (char*)d_ws;
  int* deg    = (int*)w; w += (size_t)N * 4;
  int* cur    = (int*)w; w += (size_t)N * 4;
  int* rowptr = (int*)w; w += (size_t)(N + 1) * 4;
  int* col    = (int*)w; w += (size_t)EP * 4;
  float* stats = (float*)w; w += 512 * 4;
  float* as_   = (float*)w; w += (size_t)N * 4 * 4;
  float* ad_   = (float*)w; w += (size_t)N * 4 * 4;
  float* bufA  = (float*)w; w += (size_t)N * 256 * 4;   // h1 / h2 / h3
  float* bufB  = (float*)w; w += (size_t)N * 256 * 4;   // out1/act1 / out2/act2

  // ---- CSR build (shared by both GAT layers) ----
  fill_u32_kernel<<<ceil_div(N, 256), 256, 0, stream>>>((unsigned*)deg, 0u, N);
  hist_kernel<<<ceil_div(EP, 256), 256, 0, stream>>>(ei, deg, E, N);
  scan_kernel<<<1, 1024, 0, stream>>>(deg, rowptr, N);
  copy_i32_kernel<<<ceil_div(N, 256), 256, 0, stream>>>(rowptr, cur, N);
  scatter_kernel<<<ceil_div(EP, 256), 256, 0, stream>>>(ei, cur, col, E, N);

  // ---- GAT layer 1: H=4, C=64, concat ----
  gemm_kernel<<<dim3(ceil_div(N, 64), 256 / 64), 256, 0, stream>>>(x, W1, bufA, N, 256, 128);
  alpha_kernel<<<ceil_div(N * 4, 4), 256, 0, stream>>>(bufA, a1s, a1d, as_, ad_, N * 4, 4);
  gat_aggregate_kernel<4><<<ceil_div(N, 4), 256, 0, stream>>>(bufA, as_, ad_, rowptr, col, b1, bufB, N);
  fill_u32_kernel<<<2, 256, 0, stream>>>((unsigned*)stats, 0u, 512);
  colstats_kernel<<<512, 256, 0, stream>>>(bufB, stats, N, 256);
  bn_act_kernel<<<ceil_div(N * 256, 256), 256, 0, stream>>>(bufB, stats, g1, be1, bufB, N, 256, 1);

  // ---- GAT layer 2: H=1, C=64 ----
  gemm_kernel<<<dim3(ceil_div(N, 64), 64 / 64), 256, 0, stream>>>(bufB, W2, bufA, N, 64, 256);
  alpha_kernel<<<ceil_div(N, 4), 256, 0, stream>>>(bufA, a2s, a2d, as_, ad_, N, 1);
  gat_aggregate_kernel<1><<<ceil_div(N, 4), 256, 0, stream>>>(bufA, as_, ad_, rowptr, col, b2, bufB, N);
  fill_u32_kernel<<<2, 256, 0, stream>>>((unsigned*)stats, 0u, 512);
  colstats_kernel<<<512, 256, 0, stream>>>(bufB, stats, N, 64);
  bn_act_kernel<<<ceil_div(N * 64, 256), 256, 0, stream>>>(bufB, stats, g2, be2, bufB, N, 64, 1);

  // ---- projection + final BN (bias bp cancels in BN; harness bp is zeros anyway) ----
  gemm_kernel<<<dim3(ceil_div(N, 64), 128 / 64), 256, 0, stream>>>(bufB, Wp, bufA, N, 128, 64);
  fill_u32_kernel<<<2, 256, 0, stream>>>((unsigned*)stats, 0u, 512);
  colstats_kernel<<<512, 256, 0, stream>>>(bufA, stats, N, 128);
  bn_act_kernel<<<ceil_div(N * 128, 256), 256, 0, stream>>>(bufA, stats, g3, be3, out, N, 128, 0);
}

// Round 2
// 633.958 us; speedup vs baseline: 1.4246x; 1.4246x over previous
//
#include <hip/hip_runtime.h>
#include <cstdint>
#include <cstddef>

#define NEG_SLOPE 0.2f
#define EPS_BN 1e-5f

typedef __bf16 bf16x8 __attribute__((ext_vector_type(8)));
typedef float  f32x4  __attribute__((ext_vector_type(4)));
typedef unsigned short ushort_t;

static __device__ __forceinline__ float lrelu(float x){ return x > 0.f ? x : NEG_SLOPE * x; }

static __device__ __forceinline__ float bf2f(ushort_t u){
  union { unsigned i; float f; } c; c.i = ((unsigned)u) << 16; return c.f;
}
static __device__ __forceinline__ ushort_t f2bf(float f){
  unsigned u = __float_as_uint(f);
  u += 0x7fffu + ((u >> 16) & 1u);        // RNE to bf16 (inputs finite)
  return (ushort_t)(u >> 16);
}

static inline int ceil_div(int a, int b){ return (a + b - 1) / b; }

// ---------------- utility kernels ----------------

__global__ void fill_u32_kernel(unsigned* __restrict__ p, unsigned v, int n){
  int i = blockIdx.x * 256 + threadIdx.x;
  if(i < n) p[i] = v;
}

__global__ void copy_i32_kernel(const int* __restrict__ a, int* __restrict__ b, int n){
  int i = blockIdx.x * 256 + threadIdx.x;
  if(i < n) b[i] = a[i];
}

__global__ void f2bf_kernel(const float* __restrict__ in, ushort_t* __restrict__ out, long n){
  long i = ((long)blockIdx.x * 256 + threadIdx.x) * 4;
  if(i + 3 < n){
    float4 v = *reinterpret_cast<const float4*>(in + i);
    ushort_t t0 = f2bf(v.x), t1 = f2bf(v.y), t2 = f2bf(v.z), t3 = f2bf(v.w);
    uint2 pk; pk.x = t0 | ((unsigned)t1 << 16); pk.y = t2 | ((unsigned)t3 << 16);
    *reinterpret_cast<uint2*>(out + i) = pk;
  } else {
    for(; i < n; i++) out[i] = f2bf(in[i]);
  }
}

// ---------------- CSR build (dst-sorted adjacency) ----------------

__global__ void hist_kernel(const int* __restrict__ ei, int* __restrict__ deg, int E, int N){
  int e = blockIdx.x * 256 + threadIdx.x;
  if(e >= E + N) return;
  int d = (e < E) ? ei[E + e] : (e - E);   // self loop for e >= E
  atomicAdd(&deg[d], 1);
}

__global__ __launch_bounds__(1024) void scan_kernel(const int* __restrict__ deg, int* __restrict__ rowptr, int n){
  __shared__ int wsum[16];
  __shared__ int carry_s;
  int t = threadIdx.x, lane = t & 63, wv = t >> 6;
  if(t == 0){ carry_s = 0; rowptr[0] = 0; }
  __syncthreads();
  for(int base = 0; base < n; base += 4096){
    int i0 = base + t * 4;
    int v0 = (i0     < n) ? deg[i0]     : 0;
    int v1 = (i0 + 1 < n) ? deg[i0 + 1] : 0;
    int v2 = (i0 + 2 < n) ? deg[i0 + 2] : 0;
    int v3 = (i0 + 3 < n) ? deg[i0 + 3] : 0;
    int s1 = v0 + v1, s2 = s1 + v2, s3 = s2 + v3;
    int sc = s3;
    #pragma unroll
    for(int off = 1; off < 64; off <<= 1){
      int u = __shfl_up(sc, off);
      if(lane >= off) sc += u;
    }
    if(lane == 63) wsum[wv] = sc;
    __syncthreads();
    if(wv == 0 && lane < 16){
      int ws = wsum[lane];
      #pragma unroll
      for(int off = 1; off < 16; off <<= 1){
        int u = __shfl_up(ws, off);
        if(lane >= off) ws += u;
      }
      wsum[lane] = ws;
    }
    __syncthreads();
    int excl = (sc - s3) + (wv ? wsum[wv - 1] : 0) + carry_s;
    if(i0     < n) rowptr[i0 + 1] = excl + v0;
    if(i0 + 1 < n) rowptr[i0 + 2] = excl + s1;
    if(i0 + 2 < n) rowptr[i0 + 3] = excl + s2;
    if(i0 + 3 < n) rowptr[i0 + 4] = excl + s3;
    __syncthreads();
    if(t == 1023) carry_s = excl + s3;
    __syncthreads();
  }
}

__global__ void scatter_kernel(const int* __restrict__ ei, int* __restrict__ cur,
                               int* __restrict__ col, int* __restrict__ row, int E, int N){
  int e = blockIdx.x * 256 + threadIdx.x;
  if(e >= E + N) return;
  int s, d;
  if(e < E){ s = ei[e]; d = ei[E + e]; } else { s = e - E; d = e - E; }
  int pos = atomicAdd(&cur[d], 1);
  col[pos] = s;
  row[pos] = d;
}

// ---------------- weight repack to MFMA B-fragment layout (bf16) ----------------
// slot for (t, s, lane, j): W[k = s*32 + (lane>>4)*8 + j][n = t*16 + (lane&15)]
// stored at ((t*KS + s)*64 + lane)*8 + j

__global__ void packW_kernel(const float* __restrict__ W, ushort_t* __restrict__ Wp, int K, int Nn){
  int idx = blockIdx.x * 256 + threadIdx.x;
  int KS = K >> 5;
  int total = (Nn >> 4) * KS * 64;
  if(idx >= total) return;
  int lane = idx & 63;
  int rest = idx >> 6;
  int s = rest % KS, t = rest / KS;
  int n  = t * 16 + (lane & 15);
  int k0 = s * 32 + (lane >> 4) * 8;
  ushort_t tmp[8];
  #pragma unroll
  for(int j = 0; j < 8; j++) tmp[j] = f2bf(W[(size_t)(k0 + j) * Nn + n]);
  uint4 pk;
  pk.x = tmp[0] | ((unsigned)tmp[1] << 16);
  pk.y = tmp[2] | ((unsigned)tmp[3] << 16);
  pk.z = tmp[4] | ((unsigned)tmp[5] << 16);
  pk.w = tmp[6] | ((unsigned)tmp[7] << 16);
  *reinterpret_cast<uint4*>(Wp + (size_t)idx * 8) = pk;
}

// ---------------- MFMA GEMM: C[M x Nn] = A[M x K](bf16) @ W(packed bf16) ----------------
// block = 4 waves; block tile 64 rows x 64 cols; wave handles 16 rows x 64 cols.

template<int K, bool OUT_BF16>
__global__ __launch_bounds__(256) void gemm_mfma_kernel(const ushort_t* __restrict__ A,
                                                        const ushort_t* __restrict__ Bp,
                                                        void* __restrict__ C, int M, int Nn){
  constexpr int KS = K >> 5;
  int lane = threadIdx.x & 63, wv = threadIdx.x >> 6;
  int row0 = blockIdx.x * 64 + wv * 16;
  int col0 = blockIdx.y * 64;
  int mi = lane & 15, q = lane >> 4;
  const bf16x8* arow = reinterpret_cast<const bf16x8*>(A + (size_t)(row0 + mi) * K + q * 8);
  const bf16x8* bbase = reinterpret_cast<const bf16x8*>(Bp) + ((size_t)(col0 >> 4) * KS) * 64 + lane;
  f32x4 acc[4] = {};
  #pragma unroll
  for(int s = 0; s < KS; s++){
    bf16x8 af = arow[s * 4];                       // advance 32 bf16 per k-step
    #pragma unroll
    for(int t = 0; t < 4; t++){
      bf16x8 bfr = bbase[((size_t)t * KS + s) * 64];
      acc[t] = __builtin_amdgcn_mfma_f32_16x16x32_bf16(af, bfr, acc[t], 0, 0, 0);
    }
  }
  #pragma unroll
  for(int t = 0; t < 4; t++){
    #pragma unroll
    for(int r = 0; r < 4; r++){
      int gr = row0 + q * 4 + r;
      if(gr < M){
        int gc = col0 + t * 16 + mi;
        float v = acc[t][r];
        if(OUT_BF16) ((ushort_t*)C)[(size_t)gr * Nn + gc] = f2bf(v);
        else         ((float*)   C)[(size_t)gr * Nn + gc] = v;
      }
    }
  }
}

// ---------------- alpha_src / alpha_dst dot products (bf16 features) ----------------

template<int H>
__global__ void alpha_kernel(const ushort_t* __restrict__ h, const float* __restrict__ a_src,
                             const float* __restrict__ a_dst, float* __restrict__ as_,
                             float* __restrict__ ad_, int NH){
  int wid = threadIdx.x >> 6, lane = threadIdx.x & 63;
  int gw = blockIdx.x * 4 + wid;
  if(gw >= NH) return;
  int hh = gw % H;
  float v = bf2f(h[(size_t)gw * 64 + lane]);
  float ps = v * a_src[hh * 64 + lane];
  float pd = v * a_dst[hh * 64 + lane];
  #pragma unroll
  for(int off = 32; off; off >>= 1){
    ps += __shfl_xor(ps, off);
    pd += __shfl_xor(pd, off);
  }
  if(lane == 0){ as_[gw] = ps; ad_[gw] = pd; }
}

// ---------------- per-edge softmax weights (edge-parallel, exp computed once) ----------------
// logits are tiny here (|as+ad| <~ 2) so exp without max-subtraction is exact enough;
// softmax ratio is mathematically identical.

template<int H>
__global__ void edgew_kernel(const int* __restrict__ col, const int* __restrict__ row,
                             const float* __restrict__ as_, const float* __restrict__ ad_,
                             float* __restrict__ w, int EP){
  int j = blockIdx.x * 256 + threadIdx.x;
  if(j >= EP) return;
  int s = col[j], d = row[j];
  #pragma unroll
  for(int h = 0; h < H; h++){
    float e = lrelu(as_[s * H + h] + ad_[d * H + h]);
    w[(size_t)j * H + h] = __expf(e);
  }
}

// ---------------- GAT aggregation: one wave per destination node, single pass ----------------

template<int H>
__global__ __launch_bounds__(256) void gat_aggregate_kernel(const ushort_t* __restrict__ hfeat,
                                                            const float* __restrict__ w,
                                                            const int* __restrict__ rowptr,
                                                            const int* __restrict__ col,
                                                            const float* __restrict__ bias,
                                                            float* __restrict__ out, int N){
  int wid = threadIdx.x >> 6, lane = threadIdx.x & 63;
  int n = blockIdx.x * 4 + wid;
  if(n >= N) return;
  int start = rowptr[n], end = rowptr[n + 1];
  float den[H] = {}, acc[H] = {};
  // denominator: lanes split edges, w reads fully coalesced
  for(int j = start + lane; j < end; j += 64){
    #pragma unroll
    for(int h = 0; h < H; h++) den[h] += w[(size_t)j * H + h];
  }
  #pragma unroll
  for(int h = 0; h < H; h++){
    #pragma unroll
    for(int off = 32; off; off >>= 1) den[h] += __shfl_xor(den[h], off);
    den[h] = 1.f / (den[h] + 1e-16f);
  }
  // weighted accumulate: wave walks edges, lane = channel
  for(int j = start; j < end; j++){
    int s = col[j];
    const ushort_t* hr = hfeat + (size_t)s * (H * 64);
    #pragma unroll
    for(int h = 0; h < H; h++){
      float wj = w[(size_t)j * H + h];
      acc[h] += wj * bf2f(hr[h * 64 + lane]);
    }
  }
  #pragma unroll
  for(int h = 0; h < H; h++)
    out[(size_t)n * (H * 64) + h * 64 + lane] = acc[h] * den[h] + bias[h * 64 + lane];
}

// ---------------- BatchNorm: column stats then normalize (+optional ELU) ----------------

__global__ __launch_bounds__(256) void colstats_kernel(const float* __restrict__ x, float* __restrict__ stats, int N, int C){
  int t = threadIdx.x;
  int rpb = 256 / C;
  int c = t % C;
  int rg = t / C;
  float sum = 0.f, sq = 0.f;
  for(int r = blockIdx.x * rpb + rg; r < N; r += gridDim.x * rpb){
    float v = x[(size_t)r * C + c];
    sum += v; sq += v * v;
  }
  __shared__ float ssum[256], ssq[256];
  ssum[t] = sum; ssq[t] = sq;
  __syncthreads();
  if(t < C){
    float S = 0.f, Q = 0.f;
    for(int g = 0; g < rpb; g++){ S += ssum[g * C + t]; Q += ssq[g * C + t]; }
    atomicAdd(&stats[t], S);
    atomicAdd(&stats[C + t], Q);
  }
}

template<bool OUT_BF16>
__global__ void bn_act_kernel(const float* __restrict__ x, const float* __restrict__ stats,
                              const float* __restrict__ gamma, const float* __restrict__ beta,
                              void* __restrict__ y, int N, int C, int do_elu){
  size_t i = (size_t)blockIdx.x * 256 + threadIdx.x;
  if(i >= (size_t)N * C) return;
  int c = (int)(i & (size_t)(C - 1));     // C is a power of two
  float invN = 1.f / (float)N;
  float mu = stats[c] * invN;
  float var = stats[C + c] * invN - mu * mu;
  float v = (x[i] - mu) * rsqrtf(var + EPS_BN) * gamma[c] + beta[c];
  if(do_elu) v = v > 0.f ? v : expm1f(v);
  if(OUT_BF16) ((ushort_t*)y)[i] = f2bf(v);
  else         ((float*)y)[i]    = v;
}

// ---------------- launch ----------------

extern "C" void kernel_launch(void* const* d_in, const int* in_sizes, int n_in,
                              void* d_out, int out_size, void* d_ws, size_t ws_size,
                              hipStream_t stream){
  const float* x   = (const float*)d_in[0];
  const int*   ei  = (const int*)  d_in[1];
  const float* W1  = (const float*)d_in[2];
  const float* a1s = (const float*)d_in[3];
  const float* a1d = (const float*)d_in[4];
  const float* b1  = (const float*)d_in[5];
  const float* W2  = (const float*)d_in[6];
  const float* a2s = (const float*)d_in[7];
  const float* a2d = (const float*)d_in[8];
  const float* b2  = (const float*)d_in[9];
  const float* Wp  = (const float*)d_in[10];
  const float* g1  = (const float*)d_in[12]; const float* be1 = (const float*)d_in[13];
  const float* g2  = (const float*)d_in[14]; const float* be2 = (const float*)d_in[15];
  const float* g3  = (const float*)d_in[16]; const float* be3 = (const float*)d_in[17];
  float* out = (float*)d_out;

  const int N  = in_sizes[0] / 128;
  const int E  = in_sizes[1] / 2;
  const int EP = E + N;
  const int Mpad = ((N + 63) / 64) * 64;

  // ---- workspace carve (~100 MB, lifetime-overlaid) ----
  char* p = (char*)d_ws;
  auto carve = [&](size_t bytes) -> char* {
    char* r = p; p += (bytes + 255) & ~(size_t)255; return r;
  };
  int*   deg    = (int*)carve((size_t)N * 4);
  int*   cur    = (int*)carve((size_t)N * 4);
  int*   rowptr = (int*)carve((size_t)(N + 1) * 4);
  int*   col    = (int*)carve((size_t)EP * 4);
  int*   row    = (int*)carve((size_t)EP * 4);
  float* as_    = (float*)carve((size_t)N * 4 * 4);
  float* ad_    = (float*)carve((size_t)N * 4 * 4);
  float* stats  = (float*)carve(512 * 4);
  ushort_t* W1p = (ushort_t*)carve((size_t)128 * 256 * 2);
  ushort_t* W2p = (ushort_t*)carve((size_t)256 * 64 * 2);
  ushort_t* W3p = (ushort_t*)carve((size_t)64 * 128 * 2);
  // S1: h1_bf16 -> act1_bf16 -> h3_fp32 (sequential lifetimes)
  char* S1 = carve((size_t)Mpad * 256 * 2);
  ushort_t* h1b   = (ushort_t*)S1;
  ushort_t* act1b = (ushort_t*)S1;
  float*    h3    = (float*)S1;                 // N*128*4 <= Mpad*256*2
  // S2: x_bf16 -> out1_fp32 -> { h2_bf16, out2_fp32, act2_bf16 }
  char* S2 = carve((size_t)N * 256 * 4);
  ushort_t* xb    = (ushort_t*)S2;
  float*    out1  = (float*)S2;
  ushort_t* h2b   = (ushort_t*)S2;
  float*    out2  = (float*)(S2 + (((size_t)Mpad * 64 * 2 + 255) & ~(size_t)255));
  ushort_t* act2b = (ushort_t*)((char*)out2 + (((size_t)N * 64 * 4 + 255) & ~(size_t)255));
  // S3: per-edge softmax weights (layer1 H=4; layer2 reuses with H=1)
  float* w_edge = (float*)carve((size_t)EP * 4 * 4);

  // ---- CSR build (shared by both GAT layers) ----
  fill_u32_kernel<<<ceil_div(N, 256), 256, 0, stream>>>((unsigned*)deg, 0u, N);
  hist_kernel<<<ceil_div(EP, 256), 256, 0, stream>>>(ei, deg, E, N);
  scan_kernel<<<1, 1024, 0, stream>>>(deg, rowptr, N);
  copy_i32_kernel<<<ceil_div(N, 256), 256, 0, stream>>>(rowptr, cur, N);
  scatter_kernel<<<ceil_div(EP, 256), 256, 0, stream>>>(ei, cur, col, row, E, N);

  // ---- input & weight conversion ----
  f2bf_kernel<<<ceil_div(N * 128 / 4, 256), 256, 0, stream>>>(x, xb, (long)N * 128);
  packW_kernel<<<ceil_div(16 * 4 * 64, 256), 256, 0, stream>>>(W1, W1p, 128, 256);
  packW_kernel<<<ceil_div(4 * 8 * 64, 256), 256, 0, stream>>>(W2, W2p, 256, 64);
  packW_kernel<<<ceil_div(8 * 2 * 64, 256), 256, 0, stream>>>(Wp, W3p, 64, 128);

  // ---- GAT layer 1: H=4, C=64, concat ----
  gemm_mfma_kernel<128, true><<<dim3(Mpad / 64, 4), 256, 0, stream>>>(xb, W1p, h1b, N, 256);
  alpha_kernel<4><<<ceil_div(N * 4, 4), 256, 0, stream>>>(h1b, a1s, a1d, as_, ad_, N * 4);
  edgew_kernel<4><<<ceil_div(EP, 256), 256, 0, stream>>>(col, row, as_, ad_, w_edge, EP);
  gat_aggregate_kernel<4><<<ceil_div(N, 4), 256, 0, stream>>>(h1b, w_edge, rowptr, col, b1, out1, N);
  fill_u32_kernel<<<2, 256, 0, stream>>>((unsigned*)stats, 0u, 512);
  colstats_kernel<<<512, 256, 0, stream>>>(out1, stats, N, 256);
  bn_act_kernel<true><<<ceil_div(N * 256, 256), 256, 0, stream>>>(out1, stats, g1, be1, act1b, N, 256, 1);

  // ---- GAT layer 2: H=1, C=64 ----
  gemm_mfma_kernel<256, true><<<dim3(Mpad / 64, 1), 256, 0, stream>>>(act1b, W2p, h2b, N, 64);
  alpha_kernel<1><<<ceil_div(N, 4), 256, 0, stream>>>(h2b, a2s, a2d, as_, ad_, N);
  edgew_kernel<1><<<ceil_div(EP, 256), 256, 0, stream>>>(col, row, as_, ad_, w_edge, EP);
  gat_aggregate_kernel<1><<<ceil_div(N, 4), 256, 0, stream>>>(h2b, w_edge, rowptr, col, b2, out2, N);
  fill_u32_kernel<<<2, 256, 0, stream>>>((unsigned*)stats, 0u, 512);
  colstats_kernel<<<512, 256, 0, stream>>>(out2, stats, N, 64);
  bn_act_kernel<true><<<ceil_div(N * 64, 256), 256, 0, stream>>>(out2, stats, g2, be2, act2b, N, 64, 1);

  // ---- projection + final BN ----
  gemm_mfma_kernel<64, false><<<dim3(Mpad / 64, 2), 256, 0, stream>>>(act2b, W3p, h3, N, 128);
  fill_u32_kernel<<<2, 256, 0, stream>>>((unsigned*)stats, 0u, 512);
  colstats_kernel<<<512, 256, 0, stream>>>(h3, stats, N, 128);
  bn_act_kernel<false><<<ceil_div(N * 128, 256), 256, 0, stream>>>(h3, stats, g3, be3, out, N, 128, 0);
}

// Round 3
// 487.096 us; speedup vs baseline: 1.8541x; 1.3015x over previous
//
#include <hip/hip_runtime.h>
#include <cstdint>
#include <cstddef>

#define NEG_SLOPE 0.2f
#define EPS_BN 1e-5f

typedef __bf16 bf16x8 __attribute__((ext_vector_type(8)));
typedef float  f32x4  __attribute__((ext_vector_type(4)));
typedef unsigned short ushort_t;

static __device__ __forceinline__ float lrelu(float x){ return x > 0.f ? x : NEG_SLOPE * x; }

static __device__ __forceinline__ float bf2f(ushort_t u){
  union { unsigned i; float f; } c; c.i = ((unsigned)u) << 16; return c.f;
}
static __device__ __forceinline__ ushort_t f2bf(float f){
  unsigned u = __float_as_uint(f);
  u += 0x7fffu + ((u >> 16) & 1u);        // RNE to bf16 (inputs finite)
  return (ushort_t)(u >> 16);
}
static __device__ __forceinline__ void unpk(unsigned u, float& lo, float& hi){
  lo = __uint_as_float(u << 16);
  hi = __uint_as_float(u & 0xffff0000u);
}

static inline int ceil_div(int a, int b){ return (a + b - 1) / b; }

// ---------------- utility kernels ----------------

__global__ void fill_u32_kernel(unsigned* __restrict__ p, unsigned v, int n){
  int i = blockIdx.x * 256 + threadIdx.x;
  if(i < n) p[i] = v;
}

__global__ void f2bf_kernel(const float* __restrict__ in, ushort_t* __restrict__ out, long n){
  long i = ((long)blockIdx.x * 256 + threadIdx.x) * 4;
  if(i + 3 < n){
    float4 v = *reinterpret_cast<const float4*>(in + i);
    ushort_t t0 = f2bf(v.x), t1 = f2bf(v.y), t2 = f2bf(v.z), t3 = f2bf(v.w);
    uint2 pk; pk.x = t0 | ((unsigned)t1 << 16); pk.y = t2 | ((unsigned)t3 << 16);
    *reinterpret_cast<uint2*>(out + i) = pk;
  } else {
    for(; i < n; i++) out[i] = f2bf(in[i]);
  }
}

// ---------------- CSR build (dst-sorted adjacency) ----------------

__global__ void hist_kernel(const int* __restrict__ ei, int* __restrict__ deg, int E, int N){
  int e = blockIdx.x * 256 + threadIdx.x;
  if(e >= E + N) return;
  int d = (e < E) ? ei[E + e] : (e - E);   // self loop for e >= E
  atomicAdd(&deg[d], 1);
}

// 3-phase scan: block-local (2048/block) -> partials -> add offsets.
__global__ __launch_bounds__(256) void scan1_kernel(const int* __restrict__ deg, int* __restrict__ rowptr,
                                                    int* __restrict__ cur, int* __restrict__ partials, int n){
  int t = threadIdx.x, lane = t & 63, wv = t >> 6;
  int base = blockIdx.x * 2048 + t * 8;
  int v[8]; int run = 0;
  #pragma unroll
  for(int k = 0; k < 8; k++){ int i = base + k; v[k] = (i < n) ? deg[i] : 0; run += v[k]; }
  int sc = run;
  #pragma unroll
  for(int off = 1; off < 64; off <<= 1){
    int u = __shfl_up(sc, off);
    if(lane >= off) sc += u;
  }
  __shared__ int wtot[4], woff[4];
  if(lane == 63) wtot[wv] = sc;
  __syncthreads();
  if(t == 0){
    int a = 0;
    #pragma unroll
    for(int i = 0; i < 4; i++){ woff[i] = a; a += wtot[i]; }
    partials[blockIdx.x] = a;
  }
  __syncthreads();
  int excl = (sc - run) + woff[wv];
  #pragma unroll
  for(int k = 0; k < 8; k++){
    int i = base + k;
    if(i < n){ cur[i] = excl; excl += v[k]; rowptr[i + 1] = excl; }
  }
}

__global__ void scan2_kernel(int* __restrict__ partials, int nb){
  int lane = threadIdx.x;                 // 64 threads, nb <= 64
  int v = (lane < nb) ? partials[lane] : 0;
  int sc = v;
  #pragma unroll
  for(int off = 1; off < 64; off <<= 1){
    int u = __shfl_up(sc, off);
    if(lane >= off) sc += u;
  }
  if(lane < nb) partials[lane] = sc - v;  // exclusive
}

__global__ void scan3_kernel(const int* __restrict__ partials, int* __restrict__ rowptr,
                             int* __restrict__ cur, int n){
  int i = blockIdx.x * 256 + threadIdx.x;
  if(i == 0) rowptr[0] = 0;
  if(i < n){
    int off = partials[i >> 11];
    rowptr[i + 1] += off;
    cur[i] += off;
  }
}

__global__ void scatter_kernel(const int* __restrict__ ei, int* __restrict__ cur,
                               int* __restrict__ col, int* __restrict__ row, int E, int N){
  int e = blockIdx.x * 256 + threadIdx.x;
  if(e >= E + N) return;
  int s, d;
  if(e < E){ s = ei[e]; d = ei[E + e]; } else { s = e - E; d = e - E; }
  int pos = atomicAdd(&cur[d], 1);
  col[pos] = s;
  row[pos] = d;
}

// ---------------- weight repack to MFMA B-fragment layout (bf16) ----------------

__global__ void packW_kernel(const float* __restrict__ W, ushort_t* __restrict__ Wp, int K, int Nn){
  int idx = blockIdx.x * 256 + threadIdx.x;
  int KS = K >> 5;
  int total = (Nn >> 4) * KS * 64;
  if(idx >= total) return;
  int lane = idx & 63;
  int rest = idx >> 6;
  int s = rest % KS, t = rest / KS;
  int n  = t * 16 + (lane & 15);
  int k0 = s * 32 + (lane >> 4) * 8;
  ushort_t tmp[8];
  #pragma unroll
  for(int j = 0; j < 8; j++) tmp[j] = f2bf(W[(size_t)(k0 + j) * Nn + n]);
  uint4 pk;
  pk.x = tmp[0] | ((unsigned)tmp[1] << 16);
  pk.y = tmp[2] | ((unsigned)tmp[3] << 16);
  pk.z = tmp[4] | ((unsigned)tmp[5] << 16);
  pk.w = tmp[6] | ((unsigned)tmp[7] << 16);
  *reinterpret_cast<uint4*>(Wp + (size_t)idx * 8) = pk;
}

// ---------------- MFMA GEMM with optional fused alpha epilogue ----------------
// block = 4 waves; wave: 16 rows x 64 cols. blockIdx.y = col-tile (== head when DO_ALPHA).

template<int K, bool OUT_BF16, bool DO_ALPHA>
__global__ __launch_bounds__(256) void gemm_mfma_kernel(const ushort_t* __restrict__ A,
                                                        const ushort_t* __restrict__ Bp,
                                                        void* __restrict__ C, int M, int Nn,
                                                        const float* __restrict__ a_src,
                                                        const float* __restrict__ a_dst,
                                                        float* __restrict__ as_,
                                                        float* __restrict__ ad_){
  constexpr int KS = K >> 5;
  int lane = threadIdx.x & 63, wv = threadIdx.x >> 6;
  int row0 = blockIdx.x * 64 + wv * 16;
  int col0 = blockIdx.y * 64;
  int mi = lane & 15, q = lane >> 4;
  const bf16x8* arow = reinterpret_cast<const bf16x8*>(A + (size_t)(row0 + mi) * K + q * 8);
  const bf16x8* bbase = reinterpret_cast<const bf16x8*>(Bp) + ((size_t)(col0 >> 4) * KS) * 64 + lane;
  f32x4 acc[4] = {};
  #pragma unroll
  for(int s = 0; s < KS; s++){
    bf16x8 af = arow[s * 4];
    #pragma unroll
    for(int t = 0; t < 4; t++){
      bf16x8 bfr = bbase[((size_t)t * KS + s) * 64];
      acc[t] = __builtin_amdgcn_mfma_f32_16x16x32_bf16(af, bfr, acc[t], 0, 0, 0);
    }
  }
  #pragma unroll
  for(int t = 0; t < 4; t++){
    #pragma unroll
    for(int r = 0; r < 4; r++){
      int gr = row0 + q * 4 + r;
      if(gr < M){
        int gc = col0 + t * 16 + mi;
        float v = acc[t][r];
        if(OUT_BF16) ((ushort_t*)C)[(size_t)gr * Nn + gc] = f2bf(v);
        else         ((float*)   C)[(size_t)gr * Nn + gc] = v;
      }
    }
  }
  if(DO_ALPHA){
    const int H = Nn >> 6;
    int head = blockIdx.y;
    #pragma unroll
    for(int r = 0; r < 4; r++){
      int gr = row0 + q * 4 + r;
      float ps = 0.f, pd = 0.f;
      #pragma unroll
      for(int t = 0; t < 4; t++){
        float av = acc[t][r];
        int c = head * 64 + t * 16 + mi;
        ps += av * a_src[c];
        pd += av * a_dst[c];
      }
      #pragma unroll
      for(int off = 1; off < 16; off <<= 1){
        ps += __shfl_xor(ps, off);
        pd += __shfl_xor(pd, off);
      }
      if(mi == 0 && gr < M){
        as_[(size_t)gr * H + head] = ps;
        ad_[(size_t)gr * H + head] = pd;
      }
    }
  }
}

// ---------------- per-edge softmax weights ----------------
// logits tiny (|as+ad| <~ 2): exp without max-subtraction; softmax ratio identical.

template<int H>
__global__ void edgew_kernel(const int* __restrict__ col, const int* __restrict__ row,
                             const float* __restrict__ as_, const float* __restrict__ ad_,
                             float* __restrict__ w, int EP){
  int j = blockIdx.x * 256 + threadIdx.x;
  if(j >= EP) return;
  int s = col[j], d = row[j];
  #pragma unroll
  for(int h = 0; h < H; h++){
    float e = lrelu(as_[s * H + h] + ad_[d * H + h]);
    w[(size_t)j * H + h] = __expf(e);
  }
}

// ---------------- GAT aggregation v2: one wave per dst node ----------------
// H=4: lane (g=lane>>5, l=lane&31) covers channels 8l..8l+7 via one uint4 gather;
//      two edges in flight per group-iteration, 2x unrolled. Cross-group fold via shfl_xor(32).

__global__ __launch_bounds__(256) void gat_aggregate4_kernel(const ushort_t* __restrict__ hfeat,
                                                             const float* __restrict__ w,
                                                             const int* __restrict__ rowptr,
                                                             const int* __restrict__ col,
                                                             const float* __restrict__ bias,
                                                             float* __restrict__ out, int N){
  int wid = threadIdx.x >> 6, lane = threadIdx.x & 63;
  int n = blockIdx.x * 4 + wid;
  if(n >= N) return;
  int start = rowptr[n], end = rowptr[n + 1];
  int g = lane >> 5, l = lane & 31;
  int hidx = l >> 3;                       // head of channels 8l..8l+7
  // denominator (one pass, lanes split edges)
  float d0 = 0.f, d1 = 0.f, d2 = 0.f, d3 = 0.f;
  for(int j = start + lane; j < end; j += 64){
    float4 wv4 = *reinterpret_cast<const float4*>(w + (size_t)j * 4);
    d0 += wv4.x; d1 += wv4.y; d2 += wv4.z; d3 += wv4.w;
  }
  #pragma unroll
  for(int off = 32; off; off >>= 1){
    d0 += __shfl_xor(d0, off); d1 += __shfl_xor(d1, off);
    d2 += __shfl_xor(d2, off); d3 += __shfl_xor(d3, off);
  }
  float den = (hidx == 0) ? d0 : (hidx == 1) ? d1 : (hidx == 2) ? d2 : d3;
  float dinv = 1.f / (den + 1e-16f);
  // weighted accumulate: 2 edges/iter (groups), 2x unroll
  float acc[8] = {};
  auto body = [&](int j){
    int s = col[j];
    float wj = w[(size_t)j * 4 + hidx];
    uint4 u = *reinterpret_cast<const uint4*>(hfeat + (size_t)s * 256 + 8 * l);
    float a, b;
    unpk(u.x, a, b); acc[0] += wj * a; acc[1] += wj * b;
    unpk(u.y, a, b); acc[2] += wj * a; acc[3] += wj * b;
    unpk(u.z, a, b); acc[4] += wj * a; acc[5] += wj * b;
    unpk(u.w, a, b); acc[6] += wj * a; acc[7] += wj * b;
  };
  int j = start + g;
  for(; j + 2 < end; j += 4){ body(j); body(j + 2); }
  if(j < end) body(j);
  #pragma unroll
  for(int k = 0; k < 8; k++) acc[k] += __shfl_xor(acc[k], 32);
  // write: g=0 -> channels 8l..8l+3, g=1 -> 8l+4..8l+7
  int cbase = 8 * l + g * 4;
  float4 o;
  o.x = acc[g * 4 + 0] * dinv + bias[cbase + 0];
  o.y = acc[g * 4 + 1] * dinv + bias[cbase + 1];
  o.z = acc[g * 4 + 2] * dinv + bias[cbase + 2];
  o.w = acc[g * 4 + 3] * dinv + bias[cbase + 3];
  *reinterpret_cast<float4*>(out + (size_t)n * 256 + cbase) = o;
}

// H=1: lane (g=lane>>4, l=lane&15) covers channels 4l..4l+3 via one uint2 gather;
//      four edges per iteration, 2x unrolled. Fold via shfl_xor(16,32).

__global__ __launch_bounds__(256) void gat_aggregate1_kernel(const ushort_t* __restrict__ hfeat,
                                                             const float* __restrict__ w,
                                                             const int* __restrict__ rowptr,
                                                             const int* __restrict__ col,
                                                             const float* __restrict__ bias,
                                                             float* __restrict__ out, int N){
  int wid = threadIdx.x >> 6, lane = threadIdx.x & 63;
  int n = blockIdx.x * 4 + wid;
  if(n >= N) return;
  int start = rowptr[n], end = rowptr[n + 1];
  int g = lane >> 4, l = lane & 15;
  float den = 0.f;
  for(int j = start + lane; j < end; j += 64) den += w[j];
  #pragma unroll
  for(int off = 32; off; off >>= 1) den += __shfl_xor(den, off);
  float dinv = 1.f / (den + 1e-16f);
  float acc[4] = {};
  auto body = [&](int j){
    int s = col[j];
    float wj = w[j];
    uint2 u = *reinterpret_cast<const uint2*>(hfeat + (size_t)s * 64 + 4 * l);
    float a, b;
    unpk(u.x, a, b); acc[0] += wj * a; acc[1] += wj * b;
    unpk(u.y, a, b); acc[2] += wj * a; acc[3] += wj * b;
  };
  int j = start + g;
  for(; j + 4 < end; j += 8){ body(j); body(j + 4); }
  if(j < end) body(j);
  #pragma unroll
  for(int k = 0; k < 4; k++){
    acc[k] += __shfl_xor(acc[k], 16);
    acc[k] += __shfl_xor(acc[k], 32);
  }
  if(g == 0){
    float4 o;
    o.x = acc[0] * dinv + bias[4 * l + 0];
    o.y = acc[1] * dinv + bias[4 * l + 1];
    o.z = acc[2] * dinv + bias[4 * l + 2];
    o.w = acc[3] * dinv + bias[4 * l + 3];
    *reinterpret_cast<float4*>(out + (size_t)n * 64 + 4 * l) = o;
  }
}

// ---------------- BatchNorm: column stats then normalize (+optional ELU) ----------------

__global__ __launch_bounds__(256) void colstats_kernel(const float* __restrict__ x, float* __restrict__ stats, int N, int C){
  int t = threadIdx.x;
  int rpb = 256 / C;
  int c = t % C;
  int rg = t / C;
  float sum = 0.f, sq = 0.f;
  for(int r = blockIdx.x * rpb + rg; r < N; r += gridDim.x * rpb){
    float v = x[(size_t)r * C + c];
    sum += v; sq += v * v;
  }
  __shared__ float ssum[256], ssq[256];
  ssum[t] = sum; ssq[t] = sq;
  __syncthreads();
  if(t < C){
    float S = 0.f, Q = 0.f;
    for(int g = 0; g < rpb; g++){ S += ssum[g * C + t]; Q += ssq[g * C + t]; }
    atomicAdd(&stats[t], S);
    atomicAdd(&stats[C + t], Q);
  }
}

template<bool OUT_BF16>
__global__ void bn_act_kernel(const float* __restrict__ x, const float* __restrict__ stats,
                              const float* __restrict__ gamma, const float* __restrict__ beta,
                              void* __restrict__ y, int N, int C, int do_elu){
  size_t i = (size_t)blockIdx.x * 256 + threadIdx.x;
  if(i >= (size_t)N * C) return;
  int c = (int)(i & (size_t)(C - 1));     // C is a power of two
  float invN = 1.f / (float)N;
  float mu = stats[c] * invN;
  float var = stats[C + c] * invN - mu * mu;
  float v = (x[i] - mu) * rsqrtf(var + EPS_BN) * gamma[c] + beta[c];
  if(do_elu) v = v > 0.f ? v : expm1f(v);
  if(OUT_BF16) ((ushort_t*)y)[i] = f2bf(v);
  else         ((float*)y)[i]    = v;
}

// ---------------- launch ----------------

extern "C" void kernel_launch(void* const* d_in, const int* in_sizes, int n_in,
                              void* d_out, int out_size, void* d_ws, size_t ws_size,
                              hipStream_t stream){
  const float* x   = (const float*)d_in[0];
  const int*   ei  = (const int*)  d_in[1];
  const float* W1  = (const float*)d_in[2];
  const float* a1s = (const float*)d_in[3];
  const float* a1d = (const float*)d_in[4];
  const float* b1  = (const float*)d_in[5];
  const float* W2  = (const float*)d_in[6];
  const float* a2s = (const float*)d_in[7];
  const float* a2d = (const float*)d_in[8];
  const float* b2  = (const float*)d_in[9];
  const float* Wp  = (const float*)d_in[10];
  const float* g1  = (const float*)d_in[12]; const float* be1 = (const float*)d_in[13];
  const float* g2  = (const float*)d_in[14]; const float* be2 = (const float*)d_in[15];
  const float* g3  = (const float*)d_in[16]; const float* be3 = (const float*)d_in[17];
  float* out = (float*)d_out;

  const int N  = in_sizes[0] / 128;
  const int E  = in_sizes[1] / 2;
  const int EP = E + N;
  const int Mpad = ((N + 63) / 64) * 64;
  const int NB = ceil_div(N, 2048);

  // ---- workspace carve (lifetime-overlaid) ----
  char* p = (char*)d_ws;
  auto carve = [&](size_t bytes) -> char* {
    char* r = p; p += (bytes + 255) & ~(size_t)255; return r;
  };
  int*   deg    = (int*)carve((size_t)N * 4);
  int*   cur    = (int*)carve((size_t)N * 4);
  int*   rowptr = (int*)carve((size_t)(N + 1) * 4);
  int*   col    = (int*)carve((size_t)EP * 4);
  int*   row    = (int*)carve((size_t)EP * 4);
  int*   part   = (int*)carve(64 * 4);
  float* as_    = (float*)carve((size_t)N * 4 * 4);
  float* ad_    = (float*)carve((size_t)N * 4 * 4);
  float* stats  = (float*)carve(512 * 4);
  ushort_t* W1p = (ushort_t*)carve((size_t)128 * 256 * 2);
  ushort_t* W2p = (ushort_t*)carve((size_t)256 * 64 * 2);
  ushort_t* W3p = (ushort_t*)carve((size_t)64 * 128 * 2);
  // S1: h1_bf16 -> act1_bf16 -> h3_fp32 (sequential lifetimes)
  char* S1 = carve((size_t)Mpad * 256 * 2);
  ushort_t* h1b   = (ushort_t*)S1;
  ushort_t* act1b = (ushort_t*)S1;
  float*    h3    = (float*)S1;
  // S2: x_bf16 -> out1_fp32 -> { h2_bf16, out2_fp32, act2_bf16 }
  char* S2 = carve((size_t)N * 256 * 4);
  ushort_t* xb    = (ushort_t*)S2;
  float*    out1  = (float*)S2;
  ushort_t* h2b   = (ushort_t*)S2;
  float*    out2  = (float*)(S2 + (((size_t)Mpad * 64 * 2 + 255) & ~(size_t)255));
  ushort_t* act2b = (ushort_t*)((char*)out2 + (((size_t)N * 64 * 4 + 255) & ~(size_t)255));
  float* w_edge = (float*)carve((size_t)EP * 4 * 4);

  // ---- CSR build ----
  fill_u32_kernel<<<ceil_div(N, 256), 256, 0, stream>>>((unsigned*)deg, 0u, N);
  hist_kernel<<<ceil_div(EP, 256), 256, 0, stream>>>(ei, deg, E, N);
  scan1_kernel<<<NB, 256, 0, stream>>>(deg, rowptr, cur, part, N);
  scan2_kernel<<<1, 64, 0, stream>>>(part, NB);
  scan3_kernel<<<ceil_div(N, 256), 256, 0, stream>>>(part, rowptr, cur, N);
  scatter_kernel<<<ceil_div(EP, 256), 256, 0, stream>>>(ei, cur, col, row, E, N);

  // ---- input & weight conversion ----
  f2bf_kernel<<<ceil_div(N * 128 / 4, 256), 256, 0, stream>>>(x, xb, (long)N * 128);
  packW_kernel<<<ceil_div(16 * 4 * 64, 256), 256, 0, stream>>>(W1, W1p, 128, 256);
  packW_kernel<<<ceil_div(4 * 8 * 64, 256), 256, 0, stream>>>(W2, W2p, 256, 64);
  packW_kernel<<<ceil_div(8 * 2 * 64, 256), 256, 0, stream>>>(Wp, W3p, 64, 128);

  // ---- GAT layer 1: H=4, C=64, concat ----
  gemm_mfma_kernel<128, true, true><<<dim3(Mpad / 64, 4), 256, 0, stream>>>(xb, W1p, h1b, N, 256, a1s, a1d, as_, ad_);
  edgew_kernel<4><<<ceil_div(EP, 256), 256, 0, stream>>>(col, row, as_, ad_, w_edge, EP);
  gat_aggregate4_kernel<<<ceil_div(N, 4), 256, 0, stream>>>(h1b, w_edge, rowptr, col, b1, out1, N);
  fill_u32_kernel<<<2, 256, 0, stream>>>((unsigned*)stats, 0u, 512);
  colstats_kernel<<<512, 256, 0, stream>>>(out1, stats, N, 256);
  bn_act_kernel<true><<<ceil_div(N * 256, 256), 256, 0, stream>>>(out1, stats, g1, be1, act1b, N, 256, 1);

  // ---- GAT layer 2: H=1, C=64 ----
  gemm_mfma_kernel<256, true, true><<<dim3(Mpad / 64, 1), 256, 0, stream>>>(act1b, W2p, h2b, N, 64, a2s, a2d, as_, ad_);
  edgew_kernel<1><<<ceil_div(EP, 256), 256, 0, stream>>>(col, row, as_, ad_, w_edge, EP);
  gat_aggregate1_kernel<<<ceil_div(N, 4), 256, 0, stream>>>(h2b, w_edge, rowptr, col, b2, out2, N);
  fill_u32_kernel<<<2, 256, 0, stream>>>((unsigned*)stats, 0u, 512);
  colstats_kernel<<<512, 256, 0, stream>>>(out2, stats, N, 64);
  bn_act_kernel<true><<<ceil_div(N * 64, 256), 256, 0, stream>>>(out2, stats, g2, be2, act2b, N, 64, 1);

  // ---- projection + final BN ----
  gemm_mfma_kernel<64, false, false><<<dim3(Mpad / 64, 2), 256, 0, stream>>>(act2b, W3p, h3, N, 128, nullptr, nullptr, nullptr, nullptr);
  fill_u32_kernel<<<2, 256, 0, stream>>>((unsigned*)stats, 0u, 512);
  colstats_kernel<<<512, 256, 0, stream>>>(h3, stats, N, 128);
  bn_act_kernel<false><<<ceil_div(N * 128, 256), 256, 0, stream>>>(h3, stats, g3, be3, out, N, 128, 0);
}

// Round 4
// 480.471 us; speedup vs baseline: 1.8796x; 1.0138x over previous
//
#include <hip/hip_runtime.h>
#include <cstdint>
#include <cstddef>

#define NEG_SLOPE 0.2f
#define EPS_BN 1e-5f
#define CAP 128

typedef __bf16 bf16x8 __attribute__((ext_vector_type(8)));
typedef float  f32x4  __attribute__((ext_vector_type(4)));
typedef unsigned short ushort_t;

static __device__ __forceinline__ float lrelu(float x){ return x > 0.f ? x : NEG_SLOPE * x; }
static __device__ __forceinline__ float elu(float x){ return x > 0.f ? x : __expf(x) - 1.f; }

static __device__ __forceinline__ float bf2f(ushort_t u){
  union { unsigned i; float f; } c; c.i = ((unsigned)u) << 16; return c.f;
}
static __device__ __forceinline__ ushort_t f2bf(float f){
  unsigned u = __float_as_uint(f);
  u += 0x7fffu + ((u >> 16) & 1u);        // RNE (inputs finite)
  return (ushort_t)(u >> 16);
}
static __device__ __forceinline__ void unpk(unsigned u, float& lo, float& hi){
  lo = __uint_as_float(u << 16);
  hi = __uint_as_float(u & 0xffff0000u);
}

union BF8 { bf16x8 v; ushort_t u[8]; };

static inline int ceil_div(int a, int b){ return (a + b - 1) / b; }

// ---------------- utility ----------------

__global__ void fill_u32_kernel(unsigned* __restrict__ p, unsigned v, int n){
  int i = blockIdx.x * 256 + threadIdx.x;
  if(i < n) p[i] = v;
}

// ---------------- CSR build (dst-sorted adjacency) ----------------

__global__ void hist_kernel(const int* __restrict__ ei, int* __restrict__ deg, int E, int N){
  int e = blockIdx.x * 256 + threadIdx.x;
  if(e >= E + N) return;
  int d = (e < E) ? ei[E + e] : (e - E);   // self loop for e >= E
  atomicAdd(&deg[d], 1);
}

__global__ __launch_bounds__(256) void scan1_kernel(const int* __restrict__ deg, int* __restrict__ rowptr,
                                                    int* __restrict__ cur, int* __restrict__ partials, int n){
  int t = threadIdx.x, lane = t & 63, wv = t >> 6;
  int base = blockIdx.x * 2048 + t * 8;
  int v[8]; int run = 0;
  #pragma unroll
  for(int k = 0; k < 8; k++){ int i = base + k; v[k] = (i < n) ? deg[i] : 0; run += v[k]; }
  int sc = run;
  #pragma unroll
  for(int off = 1; off < 64; off <<= 1){
    int u = __shfl_up(sc, off);
    if(lane >= off) sc += u;
  }
  __shared__ int wtot[4], woff[4];
  if(lane == 63) wtot[wv] = sc;
  __syncthreads();
  if(t == 0){
    int a = 0;
    #pragma unroll
    for(int i = 0; i < 4; i++){ woff[i] = a; a += wtot[i]; }
    partials[blockIdx.x] = a;
  }
  __syncthreads();
  int excl = (sc - run) + woff[wv];
  #pragma unroll
  for(int k = 0; k < 8; k++){
    int i = base + k;
    if(i < n){ cur[i] = excl; excl += v[k]; rowptr[i + 1] = excl; }
  }
}

__global__ void scan2_kernel(int* __restrict__ partials, int nb){
  int lane = threadIdx.x;
  int v = (lane < nb) ? partials[lane] : 0;
  int sc = v;
  #pragma unroll
  for(int off = 1; off < 64; off <<= 1){
    int u = __shfl_up(sc, off);
    if(lane >= off) sc += u;
  }
  if(lane < nb) partials[lane] = sc - v;  // exclusive
}

__global__ void scan3_kernel(const int* __restrict__ partials, int* __restrict__ rowptr,
                             int* __restrict__ cur, int n){
  int i = blockIdx.x * 256 + threadIdx.x;
  if(i == 0) rowptr[0] = 0;
  if(i < n){
    int off = partials[i >> 11];
    rowptr[i + 1] += off;
    cur[i] += off;
  }
}

__global__ void scatter_kernel(const int* __restrict__ ei, int* __restrict__ cur,
                               int* __restrict__ col, int E, int N){
  int e = blockIdx.x * 256 + threadIdx.x;
  if(e >= E + N) return;
  int s, d;
  if(e < E){ s = ei[e]; d = ei[E + e]; } else { s = e - E; d = e - E; }
  int pos = atomicAdd(&cur[d], 1);
  col[pos] = s;
}

// ---------------- weight repack to MFMA B-fragment layout (all 3 in one kernel) ----------------

static __device__ void packW_body(const float* W, ushort_t* Wp, int K, int Nn, int idx){
  int lane = idx & 63;
  int rest = idx >> 6;
  int KS = K >> 5;
  int s = rest % KS, t = rest / KS;
  int n  = t * 16 + (lane & 15);
  int k0 = s * 32 + (lane >> 4) * 8;
  ushort_t tmp[8];
  #pragma unroll
  for(int j = 0; j < 8; j++) tmp[j] = f2bf(W[(size_t)(k0 + j) * Nn + n]);
  uint4 pk;
  pk.x = tmp[0] | ((unsigned)tmp[1] << 16);
  pk.y = tmp[2] | ((unsigned)tmp[3] << 16);
  pk.z = tmp[4] | ((unsigned)tmp[5] << 16);
  pk.w = tmp[6] | ((unsigned)tmp[7] << 16);
  *reinterpret_cast<uint4*>(Wp + (size_t)idx * 8) = pk;
}

__global__ void packW_all_kernel(const float* __restrict__ W1, const float* __restrict__ W2,
                                 const float* __restrict__ W3, ushort_t* __restrict__ W1p,
                                 ushort_t* __restrict__ W2p, ushort_t* __restrict__ W3p){
  int idx = blockIdx.x * 256 + threadIdx.x;
  if(idx < 4096)       packW_body(W1, W1p, 128, 256, idx);
  else if(idx < 6144)  packW_body(W2, W2p, 256, 64,  idx - 4096);
  else if(idx < 7168)  packW_body(W3, W3p, 64,  128, idx - 6144);
}

// ---------------- unified MFMA GEMM ----------------
// AMODE 0: A fp32, convert in-register. AMODE 1: A bf16 with fused BN(scale,shift)+ELU.
// Block = 4 waves, 64 rows; each block covers ALL NT col-tiles (Nn = NT*16), so A is read once.
// H>0: fused alpha epilogue (head hh covers tiles hh*4..hh*4+3; a_src flat [H*64], c=t*16+mi).

template<int K, int NT, int AMODE, int H>
__global__ __launch_bounds__(256) void gemm_kernel(const void* __restrict__ Asrc,
                                                   const ushort_t* __restrict__ Bp,
                                                   ushort_t* __restrict__ C, int M,
                                                   const float* __restrict__ scale,
                                                   const float* __restrict__ shift,
                                                   const float* __restrict__ a_src,
                                                   const float* __restrict__ a_dst,
                                                   float* __restrict__ as_,
                                                   float* __restrict__ ad_){
  constexpr int KS = K >> 5;
  int lane = threadIdx.x & 63, wv = threadIdx.x >> 6;
  int row0 = blockIdx.x * 64 + wv * 16;
  int mi = lane & 15, q = lane >> 4;
  int arow = row0 + mi; if(arow > M - 1) arow = M - 1;   // clamp: loads safe, stores guarded
  const bf16x8* bbase = reinterpret_cast<const bf16x8*>(Bp) + lane;
  f32x4 acc[NT] = {};
  #pragma unroll
  for(int s = 0; s < KS; s++){
    BF8 cv;
    if(AMODE == 0){
      const float* ap = (const float*)Asrc + (size_t)arow * K + s * 32 + q * 8;
      float4 u0 = *reinterpret_cast<const float4*>(ap);
      float4 u1 = *reinterpret_cast<const float4*>(ap + 4);
      cv.u[0] = f2bf(u0.x); cv.u[1] = f2bf(u0.y); cv.u[2] = f2bf(u0.z); cv.u[3] = f2bf(u0.w);
      cv.u[4] = f2bf(u1.x); cv.u[5] = f2bf(u1.y); cv.u[6] = f2bf(u1.z); cv.u[7] = f2bf(u1.w);
    } else {
      const ushort_t* ap = (const ushort_t*)Asrc + (size_t)arow * K + s * 32 + q * 8;
      uint4 u = *reinterpret_cast<const uint4*>(ap);
      int c0 = s * 32 + q * 8;
      float4 sc0 = *reinterpret_cast<const float4*>(scale + c0);
      float4 sc1 = *reinterpret_cast<const float4*>(scale + c0 + 4);
      float4 sh0 = *reinterpret_cast<const float4*>(shift + c0);
      float4 sh1 = *reinterpret_cast<const float4*>(shift + c0 + 4);
      float a, b;
      unpk(u.x, a, b); cv.u[0] = f2bf(elu(a * sc0.x + sh0.x)); cv.u[1] = f2bf(elu(b * sc0.y + sh0.y));
      unpk(u.y, a, b); cv.u[2] = f2bf(elu(a * sc0.z + sh0.z)); cv.u[3] = f2bf(elu(b * sc0.w + sh0.w));
      unpk(u.z, a, b); cv.u[4] = f2bf(elu(a * sc1.x + sh1.x)); cv.u[5] = f2bf(elu(b * sc1.y + sh1.y));
      unpk(u.w, a, b); cv.u[6] = f2bf(elu(a * sc1.z + sh1.z)); cv.u[7] = f2bf(elu(b * sc1.w + sh1.w));
    }
    bf16x8 af = cv.v;
    #pragma unroll
    for(int t = 0; t < NT; t++){
      bf16x8 bfr = bbase[((size_t)t * KS + s) * 64];
      acc[t] = __builtin_amdgcn_mfma_f32_16x16x32_bf16(af, bfr, acc[t], 0, 0, 0);
    }
  }
  #pragma unroll
  for(int t = 0; t < NT; t++){
    #pragma unroll
    for(int r = 0; r < 4; r++){
      int gr = row0 + q * 4 + r;
      if(gr < M) C[(size_t)gr * (NT * 16) + t * 16 + mi] = f2bf(acc[t][r]);
    }
  }
  if(H > 0){
    #pragma unroll
    for(int hh = 0; hh < H; hh++){
      #pragma unroll
      for(int r = 0; r < 4; r++){
        float ps = 0.f, pd = 0.f;
        #pragma unroll
        for(int tt = 0; tt < 4; tt++){
          int t = hh * 4 + tt;
          float av = acc[t][r];
          int c = t * 16 + mi;
          ps += av * a_src[c];
          pd += av * a_dst[c];
        }
        #pragma unroll
        for(int off = 1; off < 16; off <<= 1){
          ps += __shfl_xor(ps, off);
          pd += __shfl_xor(pd, off);
        }
        int gr = row0 + q * 4 + r;
        if(mi == 0 && gr < M){
          as_[(size_t)gr * H + hh] = ps;
          ad_[(size_t)gr * H + hh] = pd;
        }
      }
    }
  }
}

// ---------------- fused GAT aggregation (softmax weights computed in-kernel, LDS-cached) ----------------
// H=4. logits tiny (|as+ad| <~ 2): exp without max-subtraction; softmax ratio identical.

__global__ __launch_bounds__(256) void gat_agg4_kernel(const ushort_t* __restrict__ hfeat,
                                                       const float* __restrict__ as_,
                                                       const float* __restrict__ ad_,
                                                       const int* __restrict__ rowptr,
                                                       const int* __restrict__ col,
                                                       const float* __restrict__ bias,
                                                       ushort_t* __restrict__ out, int N){
  __shared__ float wsh[4][CAP * 4];
  int wid = threadIdx.x >> 6, lane = threadIdx.x & 63;
  int n = blockIdx.x * 4 + wid;
  if(n > N - 1) n = N - 1;               // keep barrier-uniform; duplicate writes identical
  int start = rowptr[n], end = rowptr[n + 1];
  float4 adn = *reinterpret_cast<const float4*>(ad_ + (size_t)n * 4);
  // pass 1: per-edge w into LDS + denominator (lanes split edges)
  float d0 = 0.f, d1 = 0.f, d2 = 0.f, d3 = 0.f;
  for(int j = start + lane; j < end; j += 64){
    int s = col[j];
    float4 av = *reinterpret_cast<const float4*>(as_ + (size_t)s * 4);
    float w0 = __expf(lrelu(av.x + adn.x));
    float w1 = __expf(lrelu(av.y + adn.y));
    float w2 = __expf(lrelu(av.z + adn.z));
    float w3 = __expf(lrelu(av.w + adn.w));
    int jj = j - start;
    if(jj < CAP) *reinterpret_cast<float4*>(&wsh[wid][jj * 4]) = make_float4(w0, w1, w2, w3);
    d0 += w0; d1 += w1; d2 += w2; d3 += w3;
  }
  #pragma unroll
  for(int off = 32; off; off >>= 1){
    d0 += __shfl_xor(d0, off); d1 += __shfl_xor(d1, off);
    d2 += __shfl_xor(d2, off); d3 += __shfl_xor(d3, off);
  }
  __syncthreads();
  // pass 2: weighted gather-accumulate; 2 edges/iter (lane groups), 2x unroll
  int g = lane >> 5, l = lane & 31, hidx = l >> 3;
  float den = (hidx == 0) ? d0 : (hidx == 1) ? d1 : (hidx == 2) ? d2 : d3;
  float dinv = 1.f / (den + 1e-16f);
  float adh = (hidx == 0) ? adn.x : (hidx == 1) ? adn.y : (hidx == 2) ? adn.z : adn.w;
  float acc[8] = {};
  auto body = [&](int j){
    int s = col[j];
    int jj = j - start;
    float wj = (jj < CAP) ? wsh[wid][jj * 4 + hidx]
                          : __expf(lrelu(as_[(size_t)s * 4 + hidx] + adh));
    uint4 u = *reinterpret_cast<const uint4*>(hfeat + (size_t)s * 256 + 8 * l);
    float a, b;
    unpk(u.x, a, b); acc[0] += wj * a; acc[1] += wj * b;
    unpk(u.y, a, b); acc[2] += wj * a; acc[3] += wj * b;
    unpk(u.z, a, b); acc[4] += wj * a; acc[5] += wj * b;
    unpk(u.w, a, b); acc[6] += wj * a; acc[7] += wj * b;
  };
  int j = start + g;
  for(; j + 2 < end; j += 4){ body(j); body(j + 2); }
  if(j < end) body(j);
  #pragma unroll
  for(int k = 0; k < 8; k++) acc[k] += __shfl_xor(acc[k], 32);
  int cbase = 8 * l + g * 4;
  ushort_t o0 = f2bf(acc[g * 4 + 0] * dinv + bias[cbase + 0]);
  ushort_t o1 = f2bf(acc[g * 4 + 1] * dinv + bias[cbase + 1]);
  ushort_t o2 = f2bf(acc[g * 4 + 2] * dinv + bias[cbase + 2]);
  ushort_t o3 = f2bf(acc[g * 4 + 3] * dinv + bias[cbase + 3]);
  uint2 pk; pk.x = o0 | ((unsigned)o1 << 16); pk.y = o2 | ((unsigned)o3 << 16);
  *reinterpret_cast<uint2*>(out + (size_t)n * 256 + cbase) = pk;
}

// H=1 variant: 4 edges/iter (16-lane groups), uint2 gathers.

__global__ __launch_bounds__(256) void gat_agg1_kernel(const ushort_t* __restrict__ hfeat,
                                                       const float* __restrict__ as_,
                                                       const float* __restrict__ ad_,
                                                       const int* __restrict__ rowptr,
                                                       const int* __restrict__ col,
                                                       const float* __restrict__ bias,
                                                       ushort_t* __restrict__ out, int N){
  __shared__ float wsh[4][CAP];
  int wid = threadIdx.x >> 6, lane = threadIdx.x & 63;
  int n = blockIdx.x * 4 + wid;
  if(n > N - 1) n = N - 1;
  int start = rowptr[n], end = rowptr[n + 1];
  float adn = ad_[n];
  float den = 0.f;
  for(int j = start + lane; j < end; j += 64){
    int s = col[j];
    float w = __expf(lrelu(as_[s] + adn));
    int jj = j - start;
    if(jj < CAP) wsh[wid][jj] = w;
    den += w;
  }
  #pragma unroll
  for(int off = 32; off; off >>= 1) den += __shfl_xor(den, off);
  __syncthreads();
  float dinv = 1.f / (den + 1e-16f);
  int g = lane >> 4, l = lane & 15;
  float acc[4] = {};
  auto body = [&](int j){
    int s = col[j];
    int jj = j - start;
    float wj = (jj < CAP) ? wsh[wid][jj] : __expf(lrelu(as_[s] + adn));
    uint2 u = *reinterpret_cast<const uint2*>(hfeat + (size_t)s * 64 + 4 * l);
    float a, b;
    unpk(u.x, a, b); acc[0] += wj * a; acc[1] += wj * b;
    unpk(u.y, a, b); acc[2] += wj * a; acc[3] += wj * b;
  };
  int j = start + g;
  for(; j + 4 < end; j += 8){ body(j); body(j + 4); }
  if(j < end) body(j);
  #pragma unroll
  for(int k = 0; k < 4; k++){
    acc[k] += __shfl_xor(acc[k], 16);
    acc[k] += __shfl_xor(acc[k], 32);
  }
  if(g == 0){
    ushort_t o0 = f2bf(acc[0] * dinv + bias[4 * l + 0]);
    ushort_t o1 = f2bf(acc[1] * dinv + bias[4 * l + 1]);
    ushort_t o2 = f2bf(acc[2] * dinv + bias[4 * l + 2]);
    ushort_t o3 = f2bf(acc[3] * dinv + bias[4 * l + 3]);
    uint2 pk; pk.x = o0 | ((unsigned)o1 << 16); pk.y = o2 | ((unsigned)o3 << 16);
    *reinterpret_cast<uint2*>(out + (size_t)n * 64 + 4 * l) = pk;
  }
}

// ---------------- column stats (bf16 input) + last-block finalize to scale/shift ----------------

__global__ __launch_bounds__(256) void colstats_fin_kernel(const ushort_t* __restrict__ x, int N, int C,
                                                           float* __restrict__ stats,
                                                           const float* __restrict__ gamma,
                                                           const float* __restrict__ beta,
                                                           float* __restrict__ scale,
                                                           float* __restrict__ shift,
                                                           unsigned* __restrict__ ticket, int nblk){
  int t = threadIdx.x;
  int rpb = 256 / C;
  int c = t % C, rg = t / C;
  float sum = 0.f, sq = 0.f;
  for(int r = blockIdx.x * rpb + rg; r < N; r += gridDim.x * rpb){
    float v = bf2f(x[(size_t)r * C + c]);
    sum += v; sq += v * v;
  }
  __shared__ float ssum[256], ssq[256];
  ssum[t] = sum; ssq[t] = sq;
  __syncthreads();
  if(t < C){
    float S = 0.f, Q = 0.f;
    for(int g = 0; g < rpb; g++){ S += ssum[g * C + t]; Q += ssq[g * C + t]; }
    atomicAdd(&stats[t], S);
    atomicAdd(&stats[C + t], Q);
  }
  __shared__ bool is_last;
  __syncthreads();
  if(t == 0){
    __threadfence();
    unsigned prev = atomicAdd(ticket, 1u);
    is_last = (prev == (unsigned)(nblk - 1));
  }
  __syncthreads();
  if(is_last){
    for(int cc = t; cc < C; cc += 256){
      float S = atomicAdd(&stats[cc], 0.f);        // coherent read (bypasses L1)
      float Q = atomicAdd(&stats[C + cc], 0.f);
      float invN = 1.f / (float)N;
      float mu = S * invN;
      float var = Q * invN - mu * mu;
      float rs = rsqrtf(var + EPS_BN);
      float scl = rs * gamma[cc];
      scale[cc] = scl;
      shift[cc] = beta[cc] - mu * scl;
    }
  }
}

// ---------------- final BN (pure affine, fp32 out) ----------------

__global__ void bn3_kernel(const ushort_t* __restrict__ x, const float* __restrict__ scale,
                           const float* __restrict__ shift, float* __restrict__ y, long total, int cmask){
  long i = (long)blockIdx.x * 256 + threadIdx.x;
  if(i >= total) return;
  int c = (int)(i & (long)cmask);
  y[i] = bf2f(x[i]) * scale[c] + shift[c];
}

// ---------------- launch ----------------

extern "C" void kernel_launch(void* const* d_in, const int* in_sizes, int n_in,
                              void* d_out, int out_size, void* d_ws, size_t ws_size,
                              hipStream_t stream){
  const float* x   = (const float*)d_in[0];
  const int*   ei  = (const int*)  d_in[1];
  const float* W1  = (const float*)d_in[2];
  const float* a1s = (const float*)d_in[3];
  const float* a1d = (const float*)d_in[4];
  const float* b1  = (const float*)d_in[5];
  const float* W2  = (const float*)d_in[6];
  const float* a2s = (const float*)d_in[7];
  const float* a2d = (const float*)d_in[8];
  const float* b2  = (const float*)d_in[9];
  const float* Wp  = (const float*)d_in[10];
  const float* g1  = (const float*)d_in[12]; const float* be1 = (const float*)d_in[13];
  const float* g2  = (const float*)d_in[14]; const float* be2 = (const float*)d_in[15];
  const float* g3  = (const float*)d_in[16]; const float* be3 = (const float*)d_in[17];
  float* out = (float*)d_out;

  const int N  = in_sizes[0] / 128;
  const int E  = in_sizes[1] / 2;
  const int EP = E + N;
  const int Mpad = ((N + 63) / 64) * 64;
  const int NB = ceil_div(N, 2048);

  // ---- workspace carve ----
  char* p = (char*)d_ws;
  auto carve = [&](size_t bytes) -> char* {
    char* r = p; p += (bytes + 255) & ~(size_t)255; return r;
  };
  float* meta   = (float*)carve(2048 * 4);          // stats/scale/shift/tickets, zeroed with deg
  int*   deg    = (int*)carve((size_t)N * 4);       // contiguous after meta (both 256B-multiple)
  int*   cur    = (int*)carve((size_t)N * 4);
  int*   rowptr = (int*)carve((size_t)(N + 1) * 4);
  int*   col    = (int*)carve((size_t)EP * 4);
  int*   part   = (int*)carve(64 * 4);
  float* as_    = (float*)carve((size_t)N * 4 * 4);
  float* ad_    = (float*)carve((size_t)N * 4 * 4);
  ushort_t* W1p = (ushort_t*)carve((size_t)128 * 256 * 2);
  ushort_t* W2p = (ushort_t*)carve((size_t)256 * 64 * 2);
  ushort_t* W3p = (ushort_t*)carve((size_t)64 * 128 * 2);
  ushort_t* h1b   = (ushort_t*)carve((size_t)Mpad * 256 * 2);
  ushort_t* out1b = (ushort_t*)carve((size_t)Mpad * 256 * 2);
  ushort_t* h2b   = (ushort_t*)carve((size_t)Mpad * 64 * 2);
  ushort_t* out2b = (ushort_t*)carve((size_t)Mpad * 64 * 2);
  ushort_t* h3b   = (ushort_t*)carve((size_t)Mpad * 128 * 2);

  float* stats1 = meta;        float* scale1 = meta + 512;  float* shift1 = meta + 768;
  float* stats2 = meta + 1024; float* scale2 = meta + 1152; float* shift2 = meta + 1216;
  float* stats3 = meta + 1280; float* scale3 = meta + 1536; float* shift3 = meta + 1664;
  unsigned* tick = (unsigned*)(meta + 1792);

  // ---- zero meta + deg (contiguous), build CSR ----
  fill_u32_kernel<<<ceil_div(N + 2048, 256), 256, 0, stream>>>((unsigned*)meta, 0u, N + 2048);
  hist_kernel<<<ceil_div(EP, 256), 256, 0, stream>>>(ei, deg, E, N);
  scan1_kernel<<<NB, 256, 0, stream>>>(deg, rowptr, cur, part, N);
  scan2_kernel<<<1, 64, 0, stream>>>(part, NB);
  scan3_kernel<<<ceil_div(N, 256), 256, 0, stream>>>(part, rowptr, cur, N);
  scatter_kernel<<<ceil_div(EP, 256), 256, 0, stream>>>(ei, cur, col, E, N);
  packW_all_kernel<<<28, 256, 0, stream>>>(W1, W2, Wp, W1p, W2p, W3p);

  // ---- layer 1: GEMM (fp32 A, fused f2bf + alpha) -> agg -> stats ----
  gemm_kernel<128, 16, 0, 4><<<Mpad / 64, 256, 0, stream>>>(x, W1p, h1b, N, nullptr, nullptr, a1s, a1d, as_, ad_);
  gat_agg4_kernel<<<ceil_div(N, 4), 256, 0, stream>>>(h1b, as_, ad_, rowptr, col, b1, out1b, N);
  colstats_fin_kernel<<<512, 256, 0, stream>>>(out1b, N, 256, stats1, g1, be1, scale1, shift1, tick + 0, 512);

  // ---- layer 2: GEMM (fused BN1+ELU on A + alpha) -> agg -> stats ----
  gemm_kernel<256, 4, 1, 1><<<Mpad / 64, 256, 0, stream>>>(out1b, W2p, h2b, N, scale1, shift1, a2s, a2d, as_, ad_);
  gat_agg1_kernel<<<ceil_div(N, 4), 256, 0, stream>>>(h2b, as_, ad_, rowptr, col, b2, out2b, N);
  colstats_fin_kernel<<<512, 256, 0, stream>>>(out2b, N, 64, stats2, g2, be2, scale2, shift2, tick + 1, 512);

  // ---- projection: GEMM (fused BN2+ELU on A) -> stats -> final BN ----
  gemm_kernel<64, 8, 1, 0><<<Mpad / 64, 256, 0, stream>>>(out2b, W3p, h3b, N, scale2, shift2, nullptr, nullptr, nullptr, nullptr);
  colstats_fin_kernel<<<512, 256, 0, stream>>>(h3b, N, 128, stats3, g3, be3, scale3, shift3, tick + 2, 512);
  bn3_kernel<<<ceil_div(N * 128, 256), 256, 0, stream>>>(h3b, scale3, shift3, out, (long)N * 128, 127);
}

// Round 5
// 429.011 us; speedup vs baseline: 2.1051x; 1.1200x over previous
//
#include <hip/hip_runtime.h>
#include <cstdint>
#include <cstddef>

#define NEG_SLOPE 0.2f
#define EPS_BN 1e-5f

typedef __bf16 bf16x8 __attribute__((ext_vector_type(8)));
typedef float  f32x4  __attribute__((ext_vector_type(4)));
typedef unsigned short ushort_t;

static __device__ __forceinline__ float lrelu(float x){ return x > 0.f ? x : NEG_SLOPE * x; }
static __device__ __forceinline__ float elu(float x){ return x > 0.f ? x : __expf(x) - 1.f; }

static __device__ __forceinline__ float bf2f(ushort_t u){
  union { unsigned i; float f; } c; c.i = ((unsigned)u) << 16; return c.f;
}
static __device__ __forceinline__ ushort_t f2bf(float f){
  unsigned u = __float_as_uint(f);
  u += 0x7fffu + ((u >> 16) & 1u);        // RNE (inputs finite)
  return (ushort_t)(u >> 16);
}
static __device__ __forceinline__ void unpk(unsigned u, float& lo, float& hi){
  lo = __uint_as_float(u << 16);
  hi = __uint_as_float(u & 0xffff0000u);
}

union BF8 { bf16x8 v; ushort_t u[8]; };

static inline int ceil_div(int a, int b){ return (a + b - 1) / b; }

// ---------------- utility ----------------

__global__ void fill_u32_kernel(unsigned* __restrict__ p, unsigned v, int n){
  int i = blockIdx.x * 256 + threadIdx.x;
  if(i < n) p[i] = v;
}

// ---------------- CSR build (dst-sorted adjacency) ----------------

__global__ void hist_kernel(const int* __restrict__ ei, int* __restrict__ deg, int E, int N){
  int e = blockIdx.x * 256 + threadIdx.x;
  if(e >= E + N) return;
  int d = (e < E) ? ei[E + e] : (e - E);   // self loop for e >= E
  atomicAdd(&deg[d], 1);
}

// block-local scan (2048/block); LAST block (ticket) also scans the partials array.
__global__ __launch_bounds__(256) void scan1_kernel(const int* __restrict__ deg, int* __restrict__ rowptr,
                                                    int* __restrict__ cur, int* __restrict__ partials,
                                                    unsigned* __restrict__ tick, int n){
  int t = threadIdx.x, lane = t & 63, wv = t >> 6;
  int base = blockIdx.x * 2048 + t * 8;
  int v[8]; int run = 0;
  #pragma unroll
  for(int k = 0; k < 8; k++){ int i = base + k; v[k] = (i < n) ? deg[i] : 0; run += v[k]; }
  int sc = run;
  #pragma unroll
  for(int off = 1; off < 64; off <<= 1){
    int u = __shfl_up(sc, off);
    if(lane >= off) sc += u;
  }
  __shared__ int wtot[4], woff[4];
  __shared__ bool slast;
  if(lane == 63) wtot[wv] = sc;
  __syncthreads();
  if(t == 0){
    int a = 0;
    #pragma unroll
    for(int i = 0; i < 4; i++){ woff[i] = a; a += wtot[i]; }
    partials[blockIdx.x] = a;
  }
  __syncthreads();
  int excl = (sc - run) + woff[wv];
  #pragma unroll
  for(int k = 0; k < 8; k++){
    int i = base + k;
    if(i < n){ cur[i] = excl; excl += v[k]; rowptr[i + 1] = excl; }
  }
  // last block scans partials (exclusive), fused scan2
  if(t == 0){
    __threadfence();
    slast = (atomicAdd(tick, 1u) == (unsigned)(gridDim.x - 1));
  }
  __syncthreads();
  if(slast && t < 64){
    int nb = gridDim.x;
    int pv = (t < nb) ? atomicAdd(&partials[t], 0) : 0;   // coherent read
    int psc = pv;
    #pragma unroll
    for(int off = 1; off < 64; off <<= 1){
      int u = __shfl_up(psc, off);
      if(t >= off) psc += u;
    }
    if(t < nb) partials[t] = psc - pv;
  }
}

__global__ void scan3_kernel(const int* __restrict__ partials, int* __restrict__ rowptr,
                             int* __restrict__ cur, int n){
  int i = blockIdx.x * 256 + threadIdx.x;
  if(i == 0) rowptr[0] = 0;
  if(i < n){
    int off = partials[i >> 11];
    rowptr[i + 1] += off;
    cur[i] += off;
  }
}

__global__ void scatter_kernel(const int* __restrict__ ei, int* __restrict__ cur,
                               int* __restrict__ col, int E, int N){
  int e = blockIdx.x * 256 + threadIdx.x;
  if(e >= E + N) return;
  int s, d;
  if(e < E){ s = ei[e]; d = ei[E + e]; } else { s = e - E; d = e - E; }
  int pos = atomicAdd(&cur[d], 1);
  col[pos] = s;
}

// ---------------- weight repack to MFMA B-fragment layout ----------------

static __device__ void packW_body(const float* W, ushort_t* Wp, int K, int Nn, int idx){
  int lane = idx & 63;
  int rest = idx >> 6;
  int KS = K >> 5;
  int s = rest % KS, t = rest / KS;
  int n  = t * 16 + (lane & 15);
  int k0 = s * 32 + (lane >> 4) * 8;
  ushort_t tmp[8];
  #pragma unroll
  for(int j = 0; j < 8; j++) tmp[j] = f2bf(W[(size_t)(k0 + j) * Nn + n]);
  uint4 pk;
  pk.x = tmp[0] | ((unsigned)tmp[1] << 16);
  pk.y = tmp[2] | ((unsigned)tmp[3] << 16);
  pk.z = tmp[4] | ((unsigned)tmp[5] << 16);
  pk.w = tmp[6] | ((unsigned)tmp[7] << 16);
  *reinterpret_cast<uint4*>(Wp + (size_t)idx * 8) = pk;
}

__global__ void packW_all_kernel(const float* __restrict__ W1, const float* __restrict__ W2,
                                 const float* __restrict__ W3, ushort_t* __restrict__ W1p,
                                 ushort_t* __restrict__ W2p, ushort_t* __restrict__ W3p){
  int idx = blockIdx.x * 256 + threadIdx.x;
  if(idx < 4096)       packW_body(W1, W1p, 128, 256, idx);
  else if(idx < 6144)  packW_body(W2, W2p, 256, 64,  idx - 4096);
  else if(idx < 7168)  packW_body(W3, W3p, 64,  128, idx - 6144);
}

// ---------------- unified MFMA GEMM ----------------
// AMODE 0: A fp32, convert in-register. AMODE 1: A bf16 with fused BN(scale,shift)+ELU.
// Block = 4 waves, 64 rows; block covers ALL NT col-tiles, A read once.
// H>0: fused alpha epilogue.

template<int K, int NT, int AMODE, int H>
__global__ __launch_bounds__(256) void gemm_kernel(const void* __restrict__ Asrc,
                                                   const ushort_t* __restrict__ Bp,
                                                   ushort_t* __restrict__ C, int M,
                                                   const float* __restrict__ scale,
                                                   const float* __restrict__ shift,
                                                   const float* __restrict__ a_src,
                                                   const float* __restrict__ a_dst,
                                                   float* __restrict__ as_,
                                                   float* __restrict__ ad_){
  constexpr int KS = K >> 5;
  int lane = threadIdx.x & 63, wv = threadIdx.x >> 6;
  int row0 = blockIdx.x * 64 + wv * 16;
  int mi = lane & 15, q = lane >> 4;
  int arow = row0 + mi; if(arow > M - 1) arow = M - 1;   // clamp: loads safe, stores guarded
  const bf16x8* bbase = reinterpret_cast<const bf16x8*>(Bp) + lane;
  f32x4 acc[NT] = {};
  #pragma unroll
  for(int s = 0; s < KS; s++){
    BF8 cv;
    if(AMODE == 0){
      const float* ap = (const float*)Asrc + (size_t)arow * K + s * 32 + q * 8;
      float4 u0 = *reinterpret_cast<const float4*>(ap);
      float4 u1 = *reinterpret_cast<const float4*>(ap + 4);
      cv.u[0] = f2bf(u0.x); cv.u[1] = f2bf(u0.y); cv.u[2] = f2bf(u0.z); cv.u[3] = f2bf(u0.w);
      cv.u[4] = f2bf(u1.x); cv.u[5] = f2bf(u1.y); cv.u[6] = f2bf(u1.z); cv.u[7] = f2bf(u1.w);
    } else {
      const ushort_t* ap = (const ushort_t*)Asrc + (size_t)arow * K + s * 32 + q * 8;
      uint4 u = *reinterpret_cast<const uint4*>(ap);
      int c0 = s * 32 + q * 8;
      float4 sc0 = *reinterpret_cast<const float4*>(scale + c0);
      float4 sc1 = *reinterpret_cast<const float4*>(scale + c0 + 4);
      float4 sh0 = *reinterpret_cast<const float4*>(shift + c0);
      float4 sh1 = *reinterpret_cast<const float4*>(shift + c0 + 4);
      float a, b;
      unpk(u.x, a, b); cv.u[0] = f2bf(elu(a * sc0.x + sh0.x)); cv.u[1] = f2bf(elu(b * sc0.y + sh0.y));
      unpk(u.y, a, b); cv.u[2] = f2bf(elu(a * sc0.z + sh0.z)); cv.u[3] = f2bf(elu(b * sc0.w + sh0.w));
      unpk(u.z, a, b); cv.u[4] = f2bf(elu(a * sc1.x + sh1.x)); cv.u[5] = f2bf(elu(b * sc1.y + sh1.y));
      unpk(u.w, a, b); cv.u[6] = f2bf(elu(a * sc1.z + sh1.z)); cv.u[7] = f2bf(elu(b * sc1.w + sh1.w));
    }
    bf16x8 af = cv.v;
    #pragma unroll
    for(int t = 0; t < NT; t++){
      bf16x8 bfr = bbase[((size_t)t * KS + s) * 64];
      acc[t] = __builtin_amdgcn_mfma_f32_16x16x32_bf16(af, bfr, acc[t], 0, 0, 0);
    }
  }
  #pragma unroll
  for(int t = 0; t < NT; t++){
    #pragma unroll
    for(int r = 0; r < 4; r++){
      int gr = row0 + q * 4 + r;
      if(gr < M) C[(size_t)gr * (NT * 16) + t * 16 + mi] = f2bf(acc[t][r]);
    }
  }
  if(H > 0){
    #pragma unroll
    for(int hh = 0; hh < H; hh++){
      #pragma unroll
      for(int r = 0; r < 4; r++){
        float ps = 0.f, pd = 0.f;
        #pragma unroll
        for(int tt = 0; tt < 4; tt++){
          int t = hh * 4 + tt;
          float av = acc[t][r];
          int c = t * 16 + mi;
          ps += av * a_src[c];
          pd += av * a_dst[c];
        }
        #pragma unroll
        for(int off = 1; off < 16; off <<= 1){
          ps += __shfl_xor(ps, off);
          pd += __shfl_xor(pd, off);
        }
        int gr = row0 + q * 4 + r;
        if(mi == 0 && gr < M){
          as_[(size_t)gr * H + hh] = ps;
          ad_[(size_t)gr * H + hh] = pd;
        }
      }
    }
  }
}

// ---------------- single-pass GAT aggregation ----------------
// out = (sum w*h)/(sum w): no max-subtraction needed (logits tiny), so accumulate
// unnormalized acc and den together — one sweep over edges, no LDS, 4 edges in flight.
// H=4: 2 lane-groups of 32; each group-iter gathers one node's full 512B record.

__global__ __launch_bounds__(256) void gat_agg4_kernel(const ushort_t* __restrict__ hfeat,
                                                       const float* __restrict__ as_,
                                                       const float* __restrict__ ad_,
                                                       const int* __restrict__ rowptr,
                                                       const int* __restrict__ col,
                                                       const float* __restrict__ bias,
                                                       ushort_t* __restrict__ out, int N){
  int wid = threadIdx.x >> 6, lane = threadIdx.x & 63;
  int n = blockIdx.x * 4 + wid;
  if(n > N - 1) n = N - 1;
  int start = rowptr[n], end = rowptr[n + 1];
  int g = lane >> 5, l = lane & 31, hidx = l >> 3;
  float adh = ad_[(size_t)n * 4 + hidx];
  float den = 0.f;
  float acc[8] = {};
  auto body = [&](int j){
    int s = col[j];
    float w = __expf(lrelu(as_[(size_t)s * 4 + hidx] + adh));
    uint4 u = *reinterpret_cast<const uint4*>(hfeat + (size_t)s * 256 + 8 * l);
    den += w;
    float a, b;
    unpk(u.x, a, b); acc[0] += w * a; acc[1] += w * b;
    unpk(u.y, a, b); acc[2] += w * a; acc[3] += w * b;
    unpk(u.z, a, b); acc[4] += w * a; acc[5] += w * b;
    unpk(u.w, a, b); acc[6] += w * a; acc[7] += w * b;
  };
  int j = start + g;
  for(; j + 6 < end; j += 8){ body(j); body(j + 2); body(j + 4); body(j + 6); }
  for(; j < end; j += 2) body(j);
  den += __shfl_xor(den, 32);
  #pragma unroll
  for(int k = 0; k < 8; k++) acc[k] += __shfl_xor(acc[k], 32);
  float dinv = 1.f / (den + 1e-16f);
  int cbase = 8 * l + g * 4;
  ushort_t o0 = f2bf(acc[g * 4 + 0] * dinv + bias[cbase + 0]);
  ushort_t o1 = f2bf(acc[g * 4 + 1] * dinv + bias[cbase + 1]);
  ushort_t o2 = f2bf(acc[g * 4 + 2] * dinv + bias[cbase + 2]);
  ushort_t o3 = f2bf(acc[g * 4 + 3] * dinv + bias[cbase + 3]);
  uint2 pk; pk.x = o0 | ((unsigned)o1 << 16); pk.y = o2 | ((unsigned)o3 << 16);
  *reinterpret_cast<uint2*>(out + (size_t)n * 256 + cbase) = pk;
}

// H=1: 4 lane-groups of 16, uint2 gathers, 2 edges in flight per group (8 per wave).

__global__ __launch_bounds__(256) void gat_agg1_kernel(const ushort_t* __restrict__ hfeat,
                                                       const float* __restrict__ as_,
                                                       const float* __restrict__ ad_,
                                                       const int* __restrict__ rowptr,
                                                       const int* __restrict__ col,
                                                       const float* __restrict__ bias,
                                                       ushort_t* __restrict__ out, int N){
  int wid = threadIdx.x >> 6, lane = threadIdx.x & 63;
  int n = blockIdx.x * 4 + wid;
  if(n > N - 1) n = N - 1;
  int start = rowptr[n], end = rowptr[n + 1];
  int g = lane >> 4, l = lane & 15;
  float adn = ad_[n];
  float den = 0.f;
  float acc[4] = {};
  auto body = [&](int j){
    int s = col[j];
    float w = __expf(lrelu(as_[s] + adn));
    uint2 u = *reinterpret_cast<const uint2*>(hfeat + (size_t)s * 64 + 4 * l);
    den += w;
    float a, b;
    unpk(u.x, a, b); acc[0] += w * a; acc[1] += w * b;
    unpk(u.y, a, b); acc[2] += w * a; acc[3] += w * b;
  };
  int j = start + g;
  for(; j + 4 < end; j += 8){ body(j); body(j + 4); }
  if(j < end) body(j);
  den += __shfl_xor(den, 16); den += __shfl_xor(den, 32);
  #pragma unroll
  for(int k = 0; k < 4; k++){
    acc[k] += __shfl_xor(acc[k], 16);
    acc[k] += __shfl_xor(acc[k], 32);
  }
  float dinv = 1.f / (den + 1e-16f);
  if(g == 0){
    ushort_t o0 = f2bf(acc[0] * dinv + bias[4 * l + 0]);
    ushort_t o1 = f2bf(acc[1] * dinv + bias[4 * l + 1]);
    ushort_t o2 = f2bf(acc[2] * dinv + bias[4 * l + 2]);
    ushort_t o3 = f2bf(acc[3] * dinv + bias[4 * l + 3]);
    uint2 pk; pk.x = o0 | ((unsigned)o1 << 16); pk.y = o2 | ((unsigned)o3 << 16);
    *reinterpret_cast<uint2*>(out + (size_t)n * 64 + 4 * l) = pk;
  }
}

// ---------------- column stats (vectorized uint4 = 8ch/thread) + last-block finalize ----------------

template<int C>
__global__ __launch_bounds__(256) void colstats_fin_kernel(const ushort_t* __restrict__ x, int N,
                                                           float* __restrict__ stats,
                                                           const float* __restrict__ gamma,
                                                           const float* __restrict__ beta,
                                                           float* __restrict__ scale,
                                                           float* __restrict__ shift,
                                                           unsigned* __restrict__ ticket, int nblk){
  constexpr int TPR = C / 8;           // threads per row
  constexpr int RPB = 256 / TPR;       // rows per block-iter
  int t = threadIdx.x;
  int c0 = (t % TPR) * 8, rg = t / TPR;
  float sum[8] = {}, sq[8] = {};
  for(int r = blockIdx.x * RPB + rg; r < N; r += gridDim.x * RPB){
    uint4 u = *reinterpret_cast<const uint4*>(x + (size_t)r * C + c0);
    float a, b;
    unpk(u.x, a, b); sum[0] += a; sq[0] += a * a; sum[1] += b; sq[1] += b * b;
    unpk(u.y, a, b); sum[2] += a; sq[2] += a * a; sum[3] += b; sq[3] += b * b;
    unpk(u.z, a, b); sum[4] += a; sq[4] += a * a; sum[5] += b; sq[5] += b * b;
    unpk(u.w, a, b); sum[6] += a; sq[6] += a * a; sum[7] += b; sq[7] += b * b;
  }
  __shared__ float red[2][256][8];     // 16 KB
  #pragma unroll
  for(int k = 0; k < 8; k++){ red[0][t][k] = sum[k]; red[1][t][k] = sq[k]; }
  __syncthreads();
  if(t < C){
    int tr = t >> 3, k = t & 7;
    float S = 0.f, Q = 0.f;
    for(int g2 = 0; g2 < RPB; g2++){
      S += red[0][g2 * TPR + tr][k];
      Q += red[1][g2 * TPR + tr][k];
    }
    atomicAdd(&stats[t], S);
    atomicAdd(&stats[C + t], Q);
  }
  __shared__ bool is_last;
  __syncthreads();
  if(t == 0){
    __threadfence();
    is_last = (atomicAdd(ticket, 1u) == (unsigned)(nblk - 1));
  }
  __syncthreads();
  if(is_last && t < C){
    float S = atomicAdd(&stats[t], 0.f);        // coherent read
    float Q = atomicAdd(&stats[C + t], 0.f);
    float invN = 1.f / (float)N;
    float mu = S * invN;
    float var = Q * invN - mu * mu;
    float rs = rsqrtf(var + EPS_BN);
    float scl = rs * gamma[t];
    scale[t] = scl;
    shift[t] = beta[t] - mu * scl;
  }
}

// ---------------- final BN (pure affine, vectorized, fp32 out) ----------------

__global__ void bn3_kernel(const ushort_t* __restrict__ x, const float* __restrict__ scale,
                           const float* __restrict__ shift, float* __restrict__ y, long total4){
  long i = (long)blockIdx.x * 256 + threadIdx.x;
  if(i >= total4) return;
  long e0 = i * 4;
  int c0 = (int)(e0 & 127);
  uint2 u = *reinterpret_cast<const uint2*>(x + e0);
  float4 sc = *reinterpret_cast<const float4*>(scale + c0);
  float4 sh = *reinterpret_cast<const float4*>(shift + c0);
  float a, b;
  float4 o;
  unpk(u.x, a, b); o.x = a * sc.x + sh.x; o.y = b * sc.y + sh.y;
  unpk(u.y, a, b); o.z = a * sc.z + sh.z; o.w = b * sc.w + sh.w;
  *reinterpret_cast<float4*>(y + e0) = o;
}

// ---------------- launch ----------------

extern "C" void kernel_launch(void* const* d_in, const int* in_sizes, int n_in,
                              void* d_out, int out_size, void* d_ws, size_t ws_size,
                              hipStream_t stream){
  const float* x   = (const float*)d_in[0];
  const int*   ei  = (const int*)  d_in[1];
  const float* W1  = (const float*)d_in[2];
  const float* a1s = (const float*)d_in[3];
  const float* a1d = (const float*)d_in[4];
  const float* b1  = (const float*)d_in[5];
  const float* W2  = (const float*)d_in[6];
  const float* a2s = (const float*)d_in[7];
  const float* a2d = (const float*)d_in[8];
  const float* b2  = (const float*)d_in[9];
  const float* Wp  = (const float*)d_in[10];
  const float* g1  = (const float*)d_in[12]; const float* be1 = (const float*)d_in[13];
  const float* g2  = (const float*)d_in[14]; const float* be2 = (const float*)d_in[15];
  const float* g3  = (const float*)d_in[16]; const float* be3 = (const float*)d_in[17];
  float* out = (float*)d_out;

  const int N  = in_sizes[0] / 128;
  const int E  = in_sizes[1] / 2;
  const int EP = E + N;
  const int Mpad = ((N + 63) / 64) * 64;
  const int NB = ceil_div(N, 2048);

  // ---- workspace carve ----
  char* p = (char*)d_ws;
  auto carve = [&](size_t bytes) -> char* {
    char* r = p; p += (bytes + 255) & ~(size_t)255; return r;
  };
  float* meta   = (float*)carve(2048 * 4);          // stats/scale/shift/tickets, zeroed with deg
  int*   deg    = (int*)carve((size_t)N * 4);       // contiguous after meta
  int*   cur    = (int*)carve((size_t)N * 4);
  int*   rowptr = (int*)carve((size_t)(N + 1) * 4);
  int*   col    = (int*)carve((size_t)EP * 4);
  int*   part   = (int*)carve(64 * 4);
  float* as_    = (float*)carve((size_t)N * 4 * 4);
  float* ad_    = (float*)carve((size_t)N * 4 * 4);
  ushort_t* W1p = (ushort_t*)carve((size_t)128 * 256 * 2);
  ushort_t* W2p = (ushort_t*)carve((size_t)256 * 64 * 2);
  ushort_t* W3p = (ushort_t*)carve((size_t)64 * 128 * 2);
  ushort_t* h1b   = (ushort_t*)carve((size_t)Mpad * 256 * 2);
  ushort_t* out1b = (ushort_t*)carve((size_t)Mpad * 256 * 2);
  ushort_t* h2b   = (ushort_t*)carve((size_t)Mpad * 64 * 2);
  ushort_t* out2b = (ushort_t*)carve((size_t)Mpad * 64 * 2);
  ushort_t* h3b   = (ushort_t*)carve((size_t)Mpad * 128 * 2);

  float* stats1 = meta;        float* scale1 = meta + 512;  float* shift1 = meta + 768;
  float* stats2 = meta + 1024; float* scale2 = meta + 1152; float* shift2 = meta + 1216;
  float* stats3 = meta + 1280; float* scale3 = meta + 1536; float* shift3 = meta + 1664;
  unsigned* tick = (unsigned*)(meta + 1792);        // [0..2]=colstats, [3]=scan

  // ---- zero meta + deg (contiguous), build CSR ----
  fill_u32_kernel<<<ceil_div(N + 2048, 256), 256, 0, stream>>>((unsigned*)meta, 0u, N + 2048);
  hist_kernel<<<ceil_div(EP, 256), 256, 0, stream>>>(ei, deg, E, N);
  scan1_kernel<<<NB, 256, 0, stream>>>(deg, rowptr, cur, part, tick + 3, N);
  scan3_kernel<<<ceil_div(N, 256), 256, 0, stream>>>(part, rowptr, cur, N);
  scatter_kernel<<<ceil_div(EP, 256), 256, 0, stream>>>(ei, cur, col, E, N);
  packW_all_kernel<<<28, 256, 0, stream>>>(W1, W2, Wp, W1p, W2p, W3p);

  // ---- layer 1: GEMM (fp32 A, fused f2bf + alpha) -> agg -> stats ----
  gemm_kernel<128, 16, 0, 4><<<Mpad / 64, 256, 0, stream>>>(x, W1p, h1b, N, nullptr, nullptr, a1s, a1d, as_, ad_);
  gat_agg4_kernel<<<ceil_div(N, 4), 256, 0, stream>>>(h1b, as_, ad_, rowptr, col, b1, out1b, N);
  colstats_fin_kernel<256><<<512, 256, 0, stream>>>(out1b, N, stats1, g1, be1, scale1, shift1, tick + 0, 512);

  // ---- layer 2: GEMM (fused BN1+ELU on A + alpha) -> agg -> stats ----
  gemm_kernel<256, 4, 1, 1><<<Mpad / 64, 256, 0, stream>>>(out1b, W2p, h2b, N, scale1, shift1, a2s, a2d, as_, ad_);
  gat_agg1_kernel<<<ceil_div(N, 4), 256, 0, stream>>>(h2b, as_, ad_, rowptr, col, b2, out2b, N);
  colstats_fin_kernel<64><<<512, 256, 0, stream>>>(out2b, N, stats2, g2, be2, scale2, shift2, tick + 1, 512);

  // ---- projection: GEMM (fused BN2+ELU on A) -> stats -> final BN ----
  gemm_kernel<64, 8, 1, 0><<<Mpad / 64, 256, 0, stream>>>(out2b, W3p, h3b, N, scale2, shift2, nullptr, nullptr, nullptr, nullptr);
  colstats_fin_kernel<128><<<512, 256, 0, stream>>>(h3b, N, stats3, g3, be3, scale3, shift3, tick + 2, 512);
  bn3_kernel<<<ceil_div(N * 128 / 4, 256), 256, 0, stream>>>(h3b, scale3, shift3, out, (long)N * 32);
}

// Round 6
// 418.290 us; speedup vs baseline: 2.1590x; 1.0256x over previous
//
#include <hip/hip_runtime.h>
#include <cstdint>
#include <cstddef>

#define NEG_SLOPE 0.2f
#define EPS_BN 1e-5f

typedef __bf16 bf16x8 __attribute__((ext_vector_type(8)));
typedef float  f32x4  __attribute__((ext_vector_type(4)));
typedef unsigned short ushort_t;

static __device__ __forceinline__ float lrelu(float x){ return x > 0.f ? x : NEG_SLOPE * x; }
static __device__ __forceinline__ float elu(float x){ return x > 0.f ? x : __expf(x) - 1.f; }

static __device__ __forceinline__ float bf2f(ushort_t u){
  union { unsigned i; float f; } c; c.i = ((unsigned)u) << 16; return c.f;
}
static __device__ __forceinline__ ushort_t f2bf(float f){
  unsigned u = __float_as_uint(f);
  u += 0x7fffu + ((u >> 16) & 1u);        // RNE (inputs finite)
  return (ushort_t)(u >> 16);
}
static __device__ __forceinline__ void unpk(unsigned u, float& lo, float& hi){
  lo = __uint_as_float(u << 16);
  hi = __uint_as_float(u & 0xffff0000u);
}

union BF8 { bf16x8 v; ushort_t u[8]; };

static inline int ceil_div(int a, int b){ return (a + b - 1) / b; }

// ---------------- weight repack to MFMA B-fragment layout ----------------

static __device__ void packW_body(const float* W, ushort_t* Wp, int K, int Nn, int idx){
  int lane = idx & 63;
  int rest = idx >> 6;
  int KS = K >> 5;
  int s = rest % KS, t = rest / KS;
  int n  = t * 16 + (lane & 15);
  int k0 = s * 32 + (lane >> 4) * 8;
  ushort_t tmp[8];
  #pragma unroll
  for(int j = 0; j < 8; j++) tmp[j] = f2bf(W[(size_t)(k0 + j) * Nn + n]);
  uint4 pk;
  pk.x = tmp[0] | ((unsigned)tmp[1] << 16);
  pk.y = tmp[2] | ((unsigned)tmp[3] << 16);
  pk.z = tmp[4] | ((unsigned)tmp[5] << 16);
  pk.w = tmp[6] | ((unsigned)tmp[7] << 16);
  *reinterpret_cast<uint4*>(Wp + (size_t)idx * 8) = pk;
}

// init: blocks [0,28) pack all 3 weights; remaining blocks zero meta+deg (contiguous).
__global__ void init_kernel(unsigned* __restrict__ zbase, int ztotal,
                            const float* __restrict__ W1, const float* __restrict__ W2,
                            const float* __restrict__ W3, ushort_t* __restrict__ W1p,
                            ushort_t* __restrict__ W2p, ushort_t* __restrict__ W3p){
  int b = blockIdx.x;
  if(b < 28){
    int idx = b * 256 + threadIdx.x;
    if(idx < 4096)       packW_body(W1, W1p, 128, 256, idx);
    else if(idx < 6144)  packW_body(W2, W2p, 256, 64,  idx - 4096);
    else if(idx < 7168)  packW_body(W3, W3p, 64,  128, idx - 6144);
  } else {
    int i = (b - 28) * 256 + threadIdx.x;
    if(i < ztotal) zbase[i] = 0u;
  }
}

// ---------------- unified MFMA GEMM body ----------------
// AMODE 0: A fp32, convert in-register. AMODE 1: A bf16 with fused BN(scale,shift)+ELU.
// Block = 4 waves, 64 rows; block covers ALL NT col-tiles, A read once.
// H>0: fused alpha epilogue.

template<int K, int NT, int AMODE, int H>
static __device__ __forceinline__ void gemm_body(int bx, const void* __restrict__ Asrc,
                                                 const ushort_t* __restrict__ Bp,
                                                 ushort_t* __restrict__ C, int M,
                                                 const float* __restrict__ scale,
                                                 const float* __restrict__ shift,
                                                 const float* __restrict__ a_src,
                                                 const float* __restrict__ a_dst,
                                                 float* __restrict__ as_,
                                                 float* __restrict__ ad_){
  constexpr int KS = K >> 5;
  int lane = threadIdx.x & 63, wv = threadIdx.x >> 6;
  int row0 = bx * 64 + wv * 16;
  int mi = lane & 15, q = lane >> 4;
  int arow = row0 + mi; if(arow > M - 1) arow = M - 1;   // clamp: loads safe, stores guarded
  const bf16x8* bbase = reinterpret_cast<const bf16x8*>(Bp) + lane;
  f32x4 acc[NT] = {};
  #pragma unroll
  for(int s = 0; s < KS; s++){
    BF8 cv;
    if(AMODE == 0){
      const float* ap = (const float*)Asrc + (size_t)arow * K + s * 32 + q * 8;
      float4 u0 = *reinterpret_cast<const float4*>(ap);
      float4 u1 = *reinterpret_cast<const float4*>(ap + 4);
      cv.u[0] = f2bf(u0.x); cv.u[1] = f2bf(u0.y); cv.u[2] = f2bf(u0.z); cv.u[3] = f2bf(u0.w);
      cv.u[4] = f2bf(u1.x); cv.u[5] = f2bf(u1.y); cv.u[6] = f2bf(u1.z); cv.u[7] = f2bf(u1.w);
    } else {
      const ushort_t* ap = (const ushort_t*)Asrc + (size_t)arow * K + s * 32 + q * 8;
      uint4 u = *reinterpret_cast<const uint4*>(ap);
      int c0 = s * 32 + q * 8;
      float4 sc0 = *reinterpret_cast<const float4*>(scale + c0);
      float4 sc1 = *reinterpret_cast<const float4*>(scale + c0 + 4);
      float4 sh0 = *reinterpret_cast<const float4*>(shift + c0);
      float4 sh1 = *reinterpret_cast<const float4*>(shift + c0 + 4);
      float a, b;
      unpk(u.x, a, b); cv.u[0] = f2bf(elu(a * sc0.x + sh0.x)); cv.u[1] = f2bf(elu(b * sc0.y + sh0.y));
      unpk(u.y, a, b); cv.u[2] = f2bf(elu(a * sc0.z + sh0.z)); cv.u[3] = f2bf(elu(b * sc0.w + sh0.w));
      unpk(u.z, a, b); cv.u[4] = f2bf(elu(a * sc1.x + sh1.x)); cv.u[5] = f2bf(elu(b * sc1.y + sh1.y));
      unpk(u.w, a, b); cv.u[6] = f2bf(elu(a * sc1.z + sh1.z)); cv.u[7] = f2bf(elu(b * sc1.w + sh1.w));
    }
    bf16x8 af = cv.v;
    #pragma unroll
    for(int t = 0; t < NT; t++){
      bf16x8 bfr = bbase[((size_t)t * KS + s) * 64];
      acc[t] = __builtin_amdgcn_mfma_f32_16x16x32_bf16(af, bfr, acc[t], 0, 0, 0);
    }
  }
  #pragma unroll
  for(int t = 0; t < NT; t++){
    #pragma unroll
    for(int r = 0; r < 4; r++){
      int gr = row0 + q * 4 + r;
      if(gr < M) C[(size_t)gr * (NT * 16) + t * 16 + mi] = f2bf(acc[t][r]);
    }
  }
  if(H > 0){
    #pragma unroll
    for(int hh = 0; hh < H; hh++){
      #pragma unroll
      for(int r = 0; r < 4; r++){
        float ps = 0.f, pd = 0.f;
        #pragma unroll
        for(int tt = 0; tt < 4; tt++){
          int t = hh * 4 + tt;
          float av = acc[t][r];
          int c = t * 16 + mi;
          ps += av * a_src[c];
          pd += av * a_dst[c];
        }
        #pragma unroll
        for(int off = 1; off < 16; off <<= 1){
          ps += __shfl_xor(ps, off);
          pd += __shfl_xor(pd, off);
        }
        int gr = row0 + q * 4 + r;
        if(mi == 0 && gr < M){
          as_[(size_t)gr * H + hh] = ps;
          ad_[(size_t)gr * H + hh] = pd;
        }
      }
    }
  }
}

template<int K, int NT, int AMODE, int H>
__global__ __launch_bounds__(256) void gemm_kernel(const void* __restrict__ Asrc,
                                                   const ushort_t* __restrict__ Bp,
                                                   ushort_t* __restrict__ C, int M,
                                                   const float* __restrict__ scale,
                                                   const float* __restrict__ shift,
                                                   const float* __restrict__ a_src,
                                                   const float* __restrict__ a_dst,
                                                   float* __restrict__ as_,
                                                   float* __restrict__ ad_){
  gemm_body<K, NT, AMODE, H>(blockIdx.x, Asrc, Bp, C, M, scale, shift, a_src, a_dst, as_, ad_);
}

// role-split launch: blocks [0,GB) = GEMM1, blocks [GB,..) = degree histogram.
__global__ __launch_bounds__(256) void hist_gemm1_kernel(int GB, const int* __restrict__ ei,
                                                         int* __restrict__ deg, int E, int N,
                                                         const float* __restrict__ x,
                                                         const ushort_t* __restrict__ W1p,
                                                         ushort_t* __restrict__ h1b,
                                                         const float* __restrict__ a1s,
                                                         const float* __restrict__ a1d,
                                                         float* __restrict__ as_,
                                                         float* __restrict__ ad_){
  int b = blockIdx.x;
  if(b < GB){
    gemm_body<128, 16, 0, 4>(b, x, W1p, h1b, N, nullptr, nullptr, a1s, a1d, as_, ad_);
  } else {
    int e = (b - GB) * 256 + threadIdx.x;
    if(e < E + N){
      int d = (e < E) ? ei[E + e] : (e - E);   // self loop for e >= E
      atomicAdd(&deg[d], 1);
    }
  }
}

// ---------------- CSR scan: rowptr[i] = block-local EXCLUSIVE prefix; last block scans partials ----------------

__global__ __launch_bounds__(256) void scan1_kernel(const int* __restrict__ deg, int* __restrict__ rowptr,
                                                    int* __restrict__ partials,
                                                    unsigned* __restrict__ tick, int n){
  int t = threadIdx.x, lane = t & 63, wv = t >> 6;
  int base = blockIdx.x * 2048 + t * 8;
  int v[8]; int run = 0;
  #pragma unroll
  for(int k = 0; k < 8; k++){ int i = base + k; v[k] = (i < n) ? deg[i] : 0; run += v[k]; }
  int sc = run;
  #pragma unroll
  for(int off = 1; off < 64; off <<= 1){
    int u = __shfl_up(sc, off);
    if(lane >= off) sc += u;
  }
  __shared__ int wtot[4], woff[4];
  __shared__ bool slast;
  if(lane == 63) wtot[wv] = sc;
  __syncthreads();
  if(t == 0){
    int a = 0;
    #pragma unroll
    for(int i = 0; i < 4; i++){ woff[i] = a; a += wtot[i]; }
    partials[blockIdx.x] = a;
  }
  __syncthreads();
  int excl = (sc - run) + woff[wv];
  #pragma unroll
  for(int k = 0; k < 8; k++){
    int i = base + k;
    if(i < n){ rowptr[i] = excl; excl += v[k]; }
  }
  // last block converts partials to exclusive block offsets
  if(t == 0){
    __threadfence();
    slast = (atomicAdd(tick, 1u) == (unsigned)(gridDim.x - 1));
  }
  __syncthreads();
  if(slast && t < 64){
    int nb = gridDim.x;
    int pv = (t < nb) ? atomicAdd(&partials[t], 0) : 0;   // coherent read
    int psc = pv;
    #pragma unroll
    for(int off = 1; off < 64; off <<= 1){
      int u = __shfl_up(psc, off);
      if(t >= off) psc += u;
    }
    if(t < nb) partials[t] = psc - pv;
  }
}

// scatter bumps rowptr[d] (local) in place; global index = local + part[d>>11].
// Afterwards rowptr[d] + part[d>>11] == global END of segment d.
__global__ void scatter_kernel(const int* __restrict__ ei, int* __restrict__ rowptr,
                               const int* __restrict__ part, int* __restrict__ col, int E, int N){
  int e = blockIdx.x * 256 + threadIdx.x;
  if(e >= E + N) return;
  int s, d;
  if(e < E){ s = ei[e]; d = ei[E + e]; } else { s = e - E; d = e - E; }
  int pos = atomicAdd(&rowptr[d], 1) + part[d >> 11];
  col[pos] = s;
}

// ---------------- single-pass GAT aggregation, predicated batches (no serial tail) ----------------
// out = (sum w*h)/(sum w); logits tiny so no max-subtraction needed.
// H=4: 2 lane-groups of 32; 4 edges in flight per wave at all times.

__global__ __launch_bounds__(256) void gat_agg4_kernel(const ushort_t* __restrict__ hfeat,
                                                       const float* __restrict__ as_,
                                                       const float* __restrict__ ad_,
                                                       const int* __restrict__ rowptr,
                                                       const int* __restrict__ part,
                                                       const int* __restrict__ col,
                                                       const float* __restrict__ bias,
                                                       ushort_t* __restrict__ out, int N){
  int wid = threadIdx.x >> 6, lane = threadIdx.x & 63;
  int n = blockIdx.x * 4 + wid;
  if(n > N - 1) n = N - 1;
  int start = n ? rowptr[n - 1] + part[(n - 1) >> 11] : 0;
  int end   = rowptr[n] + part[n >> 11];
  int g = lane >> 5, l = lane & 31, hidx = l >> 3;
  float adh = ad_[(size_t)n * 4 + hidx];
  float den = 0.f;
  float acc[8] = {};
  int last = end - 1;
  auto body = [&](int j){
    bool live = j < end;
    int jc = live ? j : last;
    int s = col[jc];
    float w = live ? __expf(lrelu(as_[(size_t)s * 4 + hidx] + adh)) : 0.f;
    uint4 u = *reinterpret_cast<const uint4*>(hfeat + (size_t)s * 256 + 8 * l);
    den += w;
    float a, b;
    unpk(u.x, a, b); acc[0] += w * a; acc[1] += w * b;
    unpk(u.y, a, b); acc[2] += w * a; acc[3] += w * b;
    unpk(u.z, a, b); acc[4] += w * a; acc[5] += w * b;
    unpk(u.w, a, b); acc[6] += w * a; acc[7] += w * b;
  };
  for(int j = start + g; j < end; j += 8){
    body(j); body(j + 2); body(j + 4); body(j + 6);
  }
  den += __shfl_xor(den, 32);
  #pragma unroll
  for(int k = 0; k < 8; k++) acc[k] += __shfl_xor(acc[k], 32);
  float dinv = 1.f / (den + 1e-16f);
  int cbase = 8 * l + g * 4;
  ushort_t o0 = f2bf(acc[g * 4 + 0] * dinv + bias[cbase + 0]);
  ushort_t o1 = f2bf(acc[g * 4 + 1] * dinv + bias[cbase + 1]);
  ushort_t o2 = f2bf(acc[g * 4 + 2] * dinv + bias[cbase + 2]);
  ushort_t o3 = f2bf(acc[g * 4 + 3] * dinv + bias[cbase + 3]);
  uint2 pk; pk.x = o0 | ((unsigned)o1 << 16); pk.y = o2 | ((unsigned)o3 << 16);
  *reinterpret_cast<uint2*>(out + (size_t)n * 256 + cbase) = pk;
}

// H=1: 4 lane-groups of 16; 4 edges in flight per wave, predicated.

__global__ __launch_bounds__(256) void gat_agg1_kernel(const ushort_t* __restrict__ hfeat,
                                                       const float* __restrict__ as_,
                                                       const float* __restrict__ ad_,
                                                       const int* __restrict__ rowptr,
                                                       const int* __restrict__ part,
                                                       const int* __restrict__ col,
                                                       const float* __restrict__ bias,
                                                       ushort_t* __restrict__ out, int N){
  int wid = threadIdx.x >> 6, lane = threadIdx.x & 63;
  int n = blockIdx.x * 4 + wid;
  if(n > N - 1) n = N - 1;
  int start = n ? rowptr[n - 1] + part[(n - 1) >> 11] : 0;
  int end   = rowptr[n] + part[n >> 11];
  int g = lane >> 4, l = lane & 15;
  float adn = ad_[n];
  float den = 0.f;
  float acc[4] = {};
  int last = end - 1;
  auto body = [&](int j){
    bool live = j < end;
    int jc = live ? j : last;
    int s = col[jc];
    float w = live ? __expf(lrelu(as_[s] + adn)) : 0.f;
    uint2 u = *reinterpret_cast<const uint2*>(hfeat + (size_t)s * 64 + 4 * l);
    den += w;
    float a, b;
    unpk(u.x, a, b); acc[0] += w * a; acc[1] += w * b;
    unpk(u.y, a, b); acc[2] += w * a; acc[3] += w * b;
  };
  for(int j = start + g; j < end; j += 16){
    body(j); body(j + 4); body(j + 8); body(j + 12);
  }
  den += __shfl_xor(den, 16); den += __shfl_xor(den, 32);
  #pragma unroll
  for(int k = 0; k < 4; k++){
    acc[k] += __shfl_xor(acc[k], 16);
    acc[k] += __shfl_xor(acc[k], 32);
  }
  float dinv = 1.f / (den + 1e-16f);
  if(g == 0){
    ushort_t o0 = f2bf(acc[0] * dinv + bias[4 * l + 0]);
    ushort_t o1 = f2bf(acc[1] * dinv + bias[4 * l + 1]);
    ushort_t o2 = f2bf(acc[2] * dinv + bias[4 * l + 2]);
    ushort_t o3 = f2bf(acc[3] * dinv + bias[4 * l + 3]);
    uint2 pk; pk.x = o0 | ((unsigned)o1 << 16); pk.y = o2 | ((unsigned)o3 << 16);
    *reinterpret_cast<uint2*>(out + (size_t)n * 64 + 4 * l) = pk;
  }
}

// ---------------- column stats (vectorized uint4 = 8ch/thread) + last-block finalize ----------------

template<int C>
__global__ __launch_bounds__(256) void colstats_fin_kernel(const ushort_t* __restrict__ x, int N,
                                                           float* __restrict__ stats,
                                                           const float* __restrict__ gamma,
                                                           const float* __restrict__ beta,
                                                           float* __restrict__ scale,
                                                           float* __restrict__ shift,
                                                           unsigned* __restrict__ ticket, int nblk){
  constexpr int TPR = C / 8;           // threads per row
  constexpr int RPB = 256 / TPR;       // rows per block-iter
  int t = threadIdx.x;
  int c0 = (t % TPR) * 8, rg = t / TPR;
  float sum[8] = {}, sq[8] = {};
  for(int r = blockIdx.x * RPB + rg; r < N; r += gridDim.x * RPB){
    uint4 u = *reinterpret_cast<const uint4*>(x + (size_t)r * C + c0);
    float a, b;
    unpk(u.x, a, b); sum[0] += a; sq[0] += a * a; sum[1] += b; sq[1] += b * b;
    unpk(u.y, a, b); sum[2] += a; sq[2] += a * a; sum[3] += b; sq[3] += b * b;
    unpk(u.z, a, b); sum[4] += a; sq[4] += a * a; sum[5] += b; sq[5] += b * b;
    unpk(u.w, a, b); sum[6] += a; sq[6] += a * a; sum[7] += b; sq[7] += b * b;
  }
  __shared__ float red[2][256][8];     // 16 KB
  #pragma unroll
  for(int k = 0; k < 8; k++){ red[0][t][k] = sum[k]; red[1][t][k] = sq[k]; }
  __syncthreads();
  if(t < C){
    int tr = t >> 3, k = t & 7;
    float S = 0.f, Q = 0.f;
    for(int g2 = 0; g2 < RPB; g2++){
      S += red[0][g2 * TPR + tr][k];
      Q += red[1][g2 * TPR + tr][k];
    }
    atomicAdd(&stats[t], S);
    atomicAdd(&stats[C + t], Q);
  }
  __shared__ bool is_last;
  __syncthreads();
  if(t == 0){
    __threadfence();
    is_last = (atomicAdd(ticket, 1u) == (unsigned)(nblk - 1));
  }
  __syncthreads();
  if(is_last && t < C){
    float S = atomicAdd(&stats[t], 0.f);        // coherent read
    float Q = atomicAdd(&stats[C + t], 0.f);
    float invN = 1.f / (float)N;
    float mu = S * invN;
    float var = Q * invN - mu * mu;
    float rs = rsqrtf(var + EPS_BN);
    float scl = rs * gamma[t];
    scale[t] = scl;
    shift[t] = beta[t] - mu * scl;
  }
}

// ---------------- final BN (pure affine, vectorized, fp32 out) ----------------

__global__ void bn3_kernel(const ushort_t* __restrict__ x, const float* __restrict__ scale,
                           const float* __restrict__ shift, float* __restrict__ y, long total4){
  long i = (long)blockIdx.x * 256 + threadIdx.x;
  if(i >= total4) return;
  long e0 = i * 4;
  int c0 = (int)(e0 & 127);
  uint2 u = *reinterpret_cast<const uint2*>(x + e0);
  float4 sc = *reinterpret_cast<const float4*>(scale + c0);
  float4 sh = *reinterpret_cast<const float4*>(shift + c0);
  float a, b;
  float4 o;
  unpk(u.x, a, b); o.x = a * sc.x + sh.x; o.y = b * sc.y + sh.y;
  unpk(u.y, a, b); o.z = a * sc.z + sh.z; o.w = b * sc.w + sh.w;
  *reinterpret_cast<float4*>(y + e0) = o;
}

// ---------------- launch ----------------

extern "C" void kernel_launch(void* const* d_in, const int* in_sizes, int n_in,
                              void* d_out, int out_size, void* d_ws, size_t ws_size,
                              hipStream_t stream){
  const float* x   = (const float*)d_in[0];
  const int*   ei  = (const int*)  d_in[1];
  const float* W1  = (const float*)d_in[2];
  const float* a1s = (const float*)d_in[3];
  const float* a1d = (const float*)d_in[4];
  const float* b1  = (const float*)d_in[5];
  const float* W2  = (const float*)d_in[6];
  const float* a2s = (const float*)d_in[7];
  const float* a2d = (const float*)d_in[8];
  const float* b2  = (const float*)d_in[9];
  const float* Wp  = (const float*)d_in[10];
  const float* g1  = (const float*)d_in[12]; const float* be1 = (const float*)d_in[13];
  const float* g2  = (const float*)d_in[14]; const float* be2 = (const float*)d_in[15];
  const float* g3  = (const float*)d_in[16]; const float* be3 = (const float*)d_in[17];
  float* out = (float*)d_out;

  const int N  = in_sizes[0] / 128;
  const int E  = in_sizes[1] / 2;
  const int EP = E + N;
  const int Mpad = ((N + 63) / 64) * 64;
  const int NB = ceil_div(N, 2048);
  const int GB = Mpad / 64;
  const int HB = ceil_div(EP, 256);

  // ---- workspace carve ----
  char* p = (char*)d_ws;
  auto carve = [&](size_t bytes) -> char* {
    char* r = p; p += (bytes + 255) & ~(size_t)255; return r;
  };
  float* meta   = (float*)carve(2048 * 4);          // stats/scale/shift/tickets
  int*   deg    = (int*)carve((size_t)N * 4);       // contiguous after meta (both 256B-mult)
  int*   rowptr = (int*)carve((size_t)(N + 1) * 4);
  int*   col    = (int*)carve((size_t)EP * 4);
  int*   part   = (int*)carve(64 * 4);
  float* as_    = (float*)carve((size_t)N * 4 * 4);
  float* ad_    = (float*)carve((size_t)N * 4 * 4);
  ushort_t* W1p = (ushort_t*)carve((size_t)128 * 256 * 2);
  ushort_t* W2p = (ushort_t*)carve((size_t)256 * 64 * 2);
  ushort_t* W3p = (ushort_t*)carve((size_t)64 * 128 * 2);
  ushort_t* h1b   = (ushort_t*)carve((size_t)Mpad * 256 * 2);
  ushort_t* out1b = (ushort_t*)carve((size_t)Mpad * 256 * 2);
  ushort_t* h2b   = (ushort_t*)carve((size_t)Mpad * 64 * 2);
  ushort_t* out2b = (ushort_t*)carve((size_t)Mpad * 64 * 2);
  ushort_t* h3b   = (ushort_t*)carve((size_t)Mpad * 128 * 2);

  float* stats1 = meta;        float* scale1 = meta + 512;  float* shift1 = meta + 768;
  float* stats2 = meta + 1024; float* scale2 = meta + 1152; float* shift2 = meta + 1216;
  float* stats3 = meta + 1280; float* scale3 = meta + 1536; float* shift3 = meta + 1664;
  unsigned* tick = (unsigned*)(meta + 1792);        // [0..2]=colstats, [3]=scan

  // 1) zero meta+deg + pack all weights (role-split)
  init_kernel<<<28 + ceil_div(N + 2048, 256), 256, 0, stream>>>((unsigned*)meta, N + 2048,
                                                                W1, W2, Wp, W1p, W2p, W3p);
  // 2) GEMM1 (fp32 A, fused f2bf + alpha) + degree histogram (role-split)
  hist_gemm1_kernel<<<GB + HB, 256, 0, stream>>>(GB, ei, deg, E, N, x, W1p, h1b, a1s, a1d, as_, ad_);
  // 3) CSR scan (local exclusive into rowptr; last block scans partials)
  scan1_kernel<<<NB, 256, 0, stream>>>(deg, rowptr, part, tick + 3, N);
  // 4) scatter (rowptr consumed in place; global index = local + part)
  scatter_kernel<<<HB, 256, 0, stream>>>(ei, rowptr, part, col, E, N);
  // 5) layer-1 aggregation
  gat_agg4_kernel<<<ceil_div(N, 4), 256, 0, stream>>>(h1b, as_, ad_, rowptr, part, col, b1, out1b, N);
  colstats_fin_kernel<256><<<512, 256, 0, stream>>>(out1b, N, stats1, g1, be1, scale1, shift1, tick + 0, 512);
  // 6) layer 2: GEMM (fused BN1+ELU on A + alpha) -> agg -> stats
  gemm_kernel<256, 4, 1, 1><<<GB, 256, 0, stream>>>(out1b, W2p, h2b, N, scale1, shift1, a2s, a2d, as_, ad_);
  gat_agg1_kernel<<<ceil_div(N, 4), 256, 0, stream>>>(h2b, as_, ad_, rowptr, part, col, b2, out2b, N);
  colstats_fin_kernel<64><<<512, 256, 0, stream>>>(out2b, N, stats2, g2, be2, scale2, shift2, tick + 1, 512);
  // 7) projection: GEMM (fused BN2+ELU on A) -> stats -> final BN
  gemm_kernel<64, 8, 1, 0><<<GB, 256, 0, stream>>>(out2b, W3p, h3b, N, scale2, shift2, nullptr, nullptr, nullptr, nullptr);
  colstats_fin_kernel<128><<<512, 256, 0, stream>>>(h3b, N, stats3, g3, be3, scale3, shift3, tick + 2, 512);
  bn3_kernel<<<ceil_div(N * 128 / 4, 256), 256, 0, stream>>>(h3b, scale3, shift3, out, (long)N * 32);
}